// Round 1
// baseline (2022.636 us; speedup 1.0000x reference)
//
#include <hip/hip_runtime.h>
#include <math.h>

#define B_   2
#define T_   2048
#define C_   1024
#define H_   16
#define HD_  64
#define M_   (B_ * T_)   // 4096

// ---------------------------------------------------------------------------
// LayerNorm: one block per row (1024 floats), 256 threads, float4 loads.
// ---------------------------------------------------------------------------
__global__ __launch_bounds__(256) void ln_kernel(const float* __restrict__ x,
                                                 const float* __restrict__ w,
                                                 const float* __restrict__ b,
                                                 float* __restrict__ out) {
    int row = blockIdx.x;
    int t   = threadIdx.x;
    const float4* xr = (const float4*)(x + (size_t)row * C_);
    float4 v = xr[t];
    float s  = v.x + v.y + v.z + v.w;
    float sq = v.x * v.x + v.y * v.y + v.z * v.z + v.w * v.w;
#pragma unroll
    for (int off = 32; off > 0; off >>= 1) {
        s  += __shfl_down(s,  off);
        sq += __shfl_down(sq, off);
    }
    __shared__ float ss[4], ssq[4];
    int wid = t >> 6, lane = t & 63;
    if (lane == 0) { ss[wid] = s; ssq[wid] = sq; }
    __syncthreads();
    float S  = ss[0] + ss[1] + ss[2] + ss[3];
    float SQ = ssq[0] + ssq[1] + ssq[2] + ssq[3];
    float mu   = S * (1.0f / C_);
    float var  = SQ * (1.0f / C_) - mu * mu;
    float rstd = rsqrtf(var + 1e-5f);
    float4 wv = ((const float4*)w)[t];
    float4 bv = ((const float4*)b)[t];
    float4 o;
    o.x = (v.x - mu) * rstd * wv.x + bv.x;
    o.y = (v.y - mu) * rstd * wv.y + bv.y;
    o.z = (v.z - mu) * rstd * wv.z + bv.z;
    o.w = (v.w - mu) * rstd * wv.w + bv.w;
    ((float4*)(out + (size_t)row * C_))[t] = o;
}

// ---------------------------------------------------------------------------
// fp32 tiled GEMM: C[M,N] = A[M,K] @ W[K,N], 128x128 tile, BK=16,
// 256 threads, 8x8 per thread. EPI: 0=store, 1=+residual, 2=gelu.
// ---------------------------------------------------------------------------
__device__ __forceinline__ float gelu_f(float x) {
    const float c = 0.7978845608028654f;  // sqrt(2/pi)
    float x3 = x * x * x;
    return 0.5f * x * (1.0f + tanhf(c * (x + 0.044715f * x3)));
}

template <int EPI>
__global__ __launch_bounds__(256) void gemm_kernel(const float* __restrict__ A,
                                                   const float* __restrict__ W,
                                                   const float* __restrict__ R,
                                                   float* __restrict__ C,
                                                   int M, int N, int K) {
    const int BM = 128, BN = 128, BK = 16;
    __shared__ float As[BK][BM + 4];   // transposed A tile; row stride 132 fl = 16B-mult
    __shared__ float Bs[BK][BN + 4];
    int bm  = blockIdx.y * BM;
    int bn  = blockIdx.x * BN;
    int tid = threadIdx.x;
    int tx  = tid & 15, ty = tid >> 4;

    float acc[8][8];
#pragma unroll
    for (int i = 0; i < 8; i++)
#pragma unroll
        for (int j = 0; j < 8; j++) acc[i][j] = 0.0f;

    for (int k0 = 0; k0 < K; k0 += BK) {
        // A tile: 128 rows x 16 k  (512 float4, 2 per thread), store transposed
#pragma unroll
        for (int i = 0; i < 2; i++) {
            int f   = tid * 2 + i;
            int row = f >> 2;
            int kq  = (f & 3) * 4;
            float4 a = *(const float4*)(A + (size_t)(bm + row) * K + k0 + kq);
            As[kq + 0][row] = a.x;
            As[kq + 1][row] = a.y;
            As[kq + 2][row] = a.z;
            As[kq + 3][row] = a.w;
        }
        // B tile: 16 k x 128 n (512 float4, 2 per thread)
#pragma unroll
        for (int i = 0; i < 2; i++) {
            int f  = tid * 2 + i;
            int k  = f >> 5;
            int nq = (f & 31) * 4;
            float4 bvec = *(const float4*)(W + (size_t)(k0 + k) * N + bn + nq);
            *(float4*)(&Bs[k][nq]) = bvec;
        }
        __syncthreads();
#pragma unroll 4
        for (int k = 0; k < BK; k++) {
            float a[8], bb[8];
            *(float4*)(a)      = *(const float4*)(&As[k][ty * 8]);
            *(float4*)(a + 4)  = *(const float4*)(&As[k][ty * 8 + 4]);
            *(float4*)(bb)     = *(const float4*)(&Bs[k][tx * 8]);
            *(float4*)(bb + 4) = *(const float4*)(&Bs[k][tx * 8 + 4]);
#pragma unroll
            for (int i = 0; i < 8; i++)
#pragma unroll
                for (int j = 0; j < 8; j++) acc[i][j] += a[i] * bb[j];
        }
        __syncthreads();
    }

#pragma unroll
    for (int i = 0; i < 8; i++) {
        int row = bm + ty * 8 + i;
#pragma unroll
        for (int jq = 0; jq < 2; jq++) {
            int col = bn + tx * 8 + jq * 4;
            float4 o;
            o.x = acc[i][jq * 4 + 0];
            o.y = acc[i][jq * 4 + 1];
            o.z = acc[i][jq * 4 + 2];
            o.w = acc[i][jq * 4 + 3];
            if (EPI == 1) {
                float4 r4 = *(const float4*)(R + (size_t)row * N + col);
                o.x += r4.x; o.y += r4.y; o.z += r4.z; o.w += r4.w;
            } else if (EPI == 2) {
                o.x = gelu_f(o.x); o.y = gelu_f(o.y);
                o.z = gelu_f(o.z); o.w = gelu_f(o.w);
            }
            *(float4*)(C + (size_t)row * N + col) = o;
        }
    }
}

// ---------------------------------------------------------------------------
// Flash-style causal attention, fp32. One block per (q-tile of 64, b*h).
// 256 threads as 16x16; each thread owns 4 q-rows x 4 cols.
// qkv layout: [B,T,3C] with q at col h*64, k at 1024+h*64, v at 2048+h*64.
// Output y: [B,T,C].
// ---------------------------------------------------------------------------
__global__ __launch_bounds__(256) void attn_kernel(const float* __restrict__ qkv,
                                                   float* __restrict__ y) {
    __shared__ float Qst[HD_][68];  // transposed: Qst[d][qrow]
    __shared__ float Kst[HD_][68];  // transposed: Kst[d][krow]
    __shared__ float Vs[64][68];    // Vs[krow][d]
    __shared__ float Ps[64][68];    // Ps[qrow][krow]

    int qt  = blockIdx.x;
    int bh  = blockIdx.y;
    int b   = bh >> 4, h = bh & 15;
    int tid = threadIdx.x;
    int tx  = tid & 15, ty = tid >> 4;
    int q0  = qt * 64;
    const float* base = qkv + (size_t)b * T_ * (3 * C_) + h * HD_;

    // load Q tile transposed (1024 float4 total, 4 per thread)
#pragma unroll
    for (int i = 0; i < 4; i++) {
        int f   = tid * 4 + i;
        int row = f >> 4;
        int c   = (f & 15) * 4;
        float4 v = *(const float4*)(base + (size_t)(q0 + row) * (3 * C_) + c);
        Qst[c + 0][row] = v.x; Qst[c + 1][row] = v.y;
        Qst[c + 2][row] = v.z; Qst[c + 3][row] = v.w;
    }

    float m_[4], l_[4], O[4][4];
#pragma unroll
    for (int i = 0; i < 4; i++) {
        m_[i] = -INFINITY; l_[i] = 0.0f;
#pragma unroll
        for (int j = 0; j < 4; j++) O[i][j] = 0.0f;
    }

    for (int kt = 0; kt <= qt; kt++) {
        int k0 = kt * 64;
        __syncthreads();  // protect Kst/Vs/Ps reuse (also covers Q-load, iter 0)
#pragma unroll
        for (int i = 0; i < 4; i++) {
            int f   = tid * 4 + i;
            int row = f >> 4;
            int c   = (f & 15) * 4;
            float4 kv = *(const float4*)(base + C_ + (size_t)(k0 + row) * (3 * C_) + c);
            Kst[c + 0][row] = kv.x; Kst[c + 1][row] = kv.y;
            Kst[c + 2][row] = kv.z; Kst[c + 3][row] = kv.w;
            float4 vv = *(const float4*)(base + 2 * C_ + (size_t)(k0 + row) * (3 * C_) + c);
            *(float4*)(&Vs[row][c]) = vv;
        }
        __syncthreads();

        // S = Q K^T (per-thread 4x4)
        float s[4][4];
#pragma unroll
        for (int i = 0; i < 4; i++)
#pragma unroll
            for (int j = 0; j < 4; j++) s[i][j] = 0.0f;
#pragma unroll 8
        for (int d = 0; d < HD_; d++) {
            float qa[4], kb[4];
            *(float4*)qa = *(const float4*)(&Qst[d][ty * 4]);
            *(float4*)kb = *(const float4*)(&Kst[d][tx * 4]);
#pragma unroll
            for (int i = 0; i < 4; i++)
#pragma unroll
                for (int j = 0; j < 4; j++) s[i][j] += qa[i] * kb[j];
        }

        // online softmax (rows reduced across the 16 tx lanes of same ty)
        bool diag = (kt == qt);
#pragma unroll
        for (int i = 0; i < 4; i++) {
            int qg = q0 + ty * 4 + i;
            float sv[4];
#pragma unroll
            for (int j = 0; j < 4; j++) {
                float val = s[i][j] * 0.125f;  // 1/sqrt(64)
                int kg = k0 + tx * 4 + j;
                if (diag && kg > qg) val = -INFINITY;
                sv[j] = val;
            }
            float mt = fmaxf(fmaxf(sv[0], sv[1]), fmaxf(sv[2], sv[3]));
#pragma unroll
            for (int off = 1; off < 16; off <<= 1) mt = fmaxf(mt, __shfl_xor(mt, off));
            float mnew = fmaxf(m_[i], mt);
            float p[4], sum = 0.0f;
#pragma unroll
            for (int j = 0; j < 4; j++) { p[j] = __expf(sv[j] - mnew); sum += p[j]; }
#pragma unroll
            for (int off = 1; off < 16; off <<= 1) sum += __shfl_xor(sum, off);
            float alpha = __expf(m_[i] - mnew);
            l_[i] = alpha * l_[i] + sum;
            m_[i] = mnew;
#pragma unroll
            for (int j = 0; j < 4; j++) O[i][j] *= alpha;
            *(float4*)(&Ps[ty * 4 + i][tx * 4]) = make_float4(p[0], p[1], p[2], p[3]);
        }
        __syncthreads();

        // O += P @ V
#pragma unroll 4
        for (int k = 0; k < 64; k++) {
            float vv[4];
            *(float4*)vv = *(const float4*)(&Vs[k][tx * 4]);
#pragma unroll
            for (int i = 0; i < 4; i++) {
                float pv = Ps[ty * 4 + i][k];
#pragma unroll
                for (int j = 0; j < 4; j++) O[i][j] += pv * vv[j];
            }
        }
    }

    // normalize and write y[b][t][h*64 + col]
#pragma unroll
    for (int i = 0; i < 4; i++) {
        float inv = 1.0f / l_[i];
        int t = q0 + ty * 4 + i;
        float4 o = make_float4(O[i][0] * inv, O[i][1] * inv, O[i][2] * inv, O[i][3] * inv);
        *(float4*)(y + (size_t)(b * T_ + t) * C_ + h * HD_ + tx * 4) = o;
    }
}

// ---------------------------------------------------------------------------
extern "C" void kernel_launch(void* const* d_in, const int* in_sizes, int n_in,
                              void* d_out, int out_size, void* d_ws, size_t ws_size,
                              hipStream_t stream) {
    const float* x        = (const float*)d_in[0];
    const float* w_attn   = (const float*)d_in[1];
    const float* w_proj   = (const float*)d_in[2];
    const float* w_fc     = (const float*)d_in[3];
    const float* w_fcproj = (const float*)d_in[4];
    const float* ln1_w    = (const float*)d_in[5];
    const float* ln1_b    = (const float*)d_in[6];
    const float* ln2_w    = (const float*)d_in[7];
    const float* ln2_b    = (const float*)d_in[8];
    float* out = (float*)d_out;

    float* ws = (float*)d_ws;
    // workspace layout (floats)
    float* ln_o = ws;                        //  4,194,304  (reused for ln2 out)
    float* qkv  = ws + 4194304;              // 12,582,912
    float* yb   = ws + 16777216;             //  4,194,304
    float* x1   = ws + 20971520;             //  4,194,304
    float* act  = ws + 25165824;             // 16,777,216
    // total: 41,943,040 floats = 167.8 MB

    // 1. ln1(x) -> ln_o
    ln_kernel<<<M_, 256, 0, stream>>>(x, ln1_w, ln1_b, ln_o);
    // 2. qkv = ln_o @ w_attn   [4096,1024]x[1024,3072]
    gemm_kernel<0><<<dim3(3072 / 128, M_ / 128), 256, 0, stream>>>(
        ln_o, w_attn, nullptr, qkv, M_, 3 * C_, C_);
    // 3. attention -> yb [B,T,C]
    attn_kernel<<<dim3(T_ / 64, B_ * H_), 256, 0, stream>>>(qkv, yb);
    // 4. x1 = yb @ w_proj + x
    gemm_kernel<1><<<dim3(1024 / 128, M_ / 128), 256, 0, stream>>>(
        yb, w_proj, x, x1, M_, C_, C_);
    // 5. ln2(x1) -> ln_o (reuse)
    ln_kernel<<<M_, 256, 0, stream>>>(x1, ln2_w, ln2_b, ln_o);
    // 6. act = gelu(ln_o @ w_fc)   [4096,1024]x[1024,4096]
    gemm_kernel<2><<<dim3(4096 / 128, M_ / 128), 256, 0, stream>>>(
        ln_o, w_fc, nullptr, act, M_, 4 * C_, C_);
    // 7. out = act @ w_fcproj + x1  [4096,4096]x[4096,1024]
    gemm_kernel<1><<<dim3(1024 / 128, M_ / 128), 256, 0, stream>>>(
        act, w_fcproj, x1, out, M_, C_, 4 * C_);
}

// Round 2
// 1175.749 us; speedup vs baseline: 1.7203x; 1.7203x over previous
//
#include <hip/hip_runtime.h>
#include <math.h>

#define B_   2
#define T_   2048
#define C_   1024
#define H_   16
#define HD_  64
#define M_   (B_ * T_)   // 4096

typedef __attribute__((ext_vector_type(8))) short short8;
typedef __attribute__((ext_vector_type(4))) float floatx4;
typedef __attribute__((ext_vector_type(8))) unsigned short ushort8v;

// split fp32 -> bf16 hi (RNE) + bf16 lo (RNE of remainder)
__device__ __forceinline__ void splitf(float x, unsigned short& h, unsigned short& l) {
    unsigned u  = __float_as_uint(x);
    unsigned hr = (u + 0x7fffu + ((u >> 16) & 1u)) >> 16;
    h = (unsigned short)hr;
    float r = x - __uint_as_float(hr << 16);
    unsigned ur = __float_as_uint(r);
    l = (unsigned short)((ur + 0x7fffu + ((ur >> 16) & 1u)) >> 16);
}

__device__ __forceinline__ void gload16(const void* g, void* l) {
    __builtin_amdgcn_global_load_lds(
        (const __attribute__((address_space(1))) unsigned int*)g,
        (__attribute__((address_space(3))) unsigned int*)l, 16, 0, 0);
}

__device__ __forceinline__ float gelu_f(float x) {
    const float c = 0.7978845608028654f;  // sqrt(2/pi)
    float x3 = x * x * x;
    return 0.5f * x * (1.0f + tanhf(c * (x + 0.044715f * x3)));
}

// ---------------------------------------------------------------------------
// LayerNorm: one block per row, outputs hi/lo bf16.
// ---------------------------------------------------------------------------
__global__ __launch_bounds__(256) void ln_kernel(const float* __restrict__ x,
                                                 const float* __restrict__ w,
                                                 const float* __restrict__ b,
                                                 unsigned short* __restrict__ oh,
                                                 unsigned short* __restrict__ ol) {
    int row = blockIdx.x;
    int t   = threadIdx.x;
    const float4* xr = (const float4*)(x + (size_t)row * C_);
    float4 v = xr[t];
    float s  = v.x + v.y + v.z + v.w;
    float sq = v.x * v.x + v.y * v.y + v.z * v.z + v.w * v.w;
#pragma unroll
    for (int off = 32; off > 0; off >>= 1) {
        s  += __shfl_down(s,  off);
        sq += __shfl_down(sq, off);
    }
    __shared__ float ss[4], ssq[4];
    int wid = t >> 6, lane = t & 63;
    if (lane == 0) { ss[wid] = s; ssq[wid] = sq; }
    __syncthreads();
    float S  = ss[0] + ss[1] + ss[2] + ss[3];
    float SQ = ssq[0] + ssq[1] + ssq[2] + ssq[3];
    float mu   = S * (1.0f / C_);
    float var  = SQ * (1.0f / C_) - mu * mu;
    float rstd = rsqrtf(var + 1e-5f);
    float4 wv = ((const float4*)w)[t];
    float4 bv = ((const float4*)b)[t];
    float o0 = (v.x - mu) * rstd * wv.x + bv.x;
    float o1 = (v.y - mu) * rstd * wv.y + bv.y;
    float o2 = (v.z - mu) * rstd * wv.z + bv.z;
    float o3 = (v.w - mu) * rstd * wv.w + bv.w;
    ushort4 hv, lv;
    splitf(o0, hv.x, lv.x); splitf(o1, hv.y, lv.y);
    splitf(o2, hv.z, lv.z); splitf(o3, hv.w, lv.w);
    *(ushort4*)(oh + (size_t)row * C_ + t * 4) = hv;
    *(ushort4*)(ol + (size_t)row * C_ + t * 4) = lv;
}

// ---------------------------------------------------------------------------
// Weight convert + transpose: W [K][N] f32 -> Wt_hi/lo [N][K] bf16.
// 64x64 tiles, 256 threads.
// ---------------------------------------------------------------------------
__global__ __launch_bounds__(256) void wtrans_kernel(const float* __restrict__ W,
                                                     unsigned short* __restrict__ th,
                                                     unsigned short* __restrict__ tl,
                                                     int K, int N) {
    __shared__ unsigned int tile[64][65];  // hi | lo<<16
    int n0 = blockIdx.x * 64, k0 = blockIdx.y * 64;
    int t  = threadIdx.x;
    int tc = (t & 15) * 4, tr = t >> 4;
#pragma unroll
    for (int it = 0; it < 4; it++) {
        int kr = it * 16 + tr;
        float4 v = *(const float4*)(W + (size_t)(k0 + kr) * N + n0 + tc);
        unsigned short hh, ll;
        splitf(v.x, hh, ll); tile[kr][tc + 0] = (unsigned)hh | ((unsigned)ll << 16);
        splitf(v.y, hh, ll); tile[kr][tc + 1] = (unsigned)hh | ((unsigned)ll << 16);
        splitf(v.z, hh, ll); tile[kr][tc + 2] = (unsigned)hh | ((unsigned)ll << 16);
        splitf(v.w, hh, ll); tile[kr][tc + 3] = (unsigned)hh | ((unsigned)ll << 16);
    }
    __syncthreads();
    int nl = t >> 2, kc = (t & 3) * 16;
    ushort8v h0, h1, l0, l1;
#pragma unroll
    for (int e = 0; e < 8; e++) {
        unsigned u = tile[kc + e][nl];
        h0[e] = (unsigned short)(u & 0xffff); l0[e] = (unsigned short)(u >> 16);
    }
#pragma unroll
    for (int e = 0; e < 8; e++) {
        unsigned u = tile[kc + 8 + e][nl];
        h1[e] = (unsigned short)(u & 0xffff); l1[e] = (unsigned short)(u >> 16);
    }
    size_t o = (size_t)(n0 + nl) * K + k0 + kc;
    *(ushort8v*)(th + o)     = h0;
    *(ushort8v*)(th + o + 8) = h1;
    *(ushort8v*)(tl + o)     = l0;
    *(ushort8v*)(tl + o + 8) = l1;
}

// ---------------------------------------------------------------------------
// Split-bf16 MFMA GEMM: C[M,N] = A[M,K] @ B[K,N], B given transposed [N][K].
// A,B as hi/lo bf16 pairs; 3 MFMA per fragment (hh, hl, lh).
// 128x128 tile, BK=32, 4 waves 2x2, each 64x64 (4x4 frags of 16x16x32).
// LDS in fragment order: subtile sf (16 rows x 32 k) = 1024B lane-ordered.
// EPI: 0 = store f32; 1 = store f32 + residual; 2 = gelu -> hi/lo bf16.
// ---------------------------------------------------------------------------
template <int EPI>
__global__ __launch_bounds__(256) void mfma_gemm(
    const unsigned short* __restrict__ Ah, const unsigned short* __restrict__ Al,
    const unsigned short* __restrict__ Bh, const unsigned short* __restrict__ Bl,
    const float* __restrict__ R, float* __restrict__ Cf,
    unsigned short* __restrict__ Ch, unsigned short* __restrict__ Cl,
    int N, int K) {
    __shared__ unsigned short lAh[128 * 32], lAl[128 * 32];
    __shared__ unsigned short lBh[128 * 32], lBl[128 * 32];
    int tid = threadIdx.x, lane = tid & 63, w = tid >> 6;
    int wr = w >> 1, wc = w & 1;
    int bm = blockIdx.y * 128, bn = blockIdx.x * 128;
    int r15 = lane & 15, hq = lane >> 4;

    floatx4 acc[4][4];
#pragma unroll
    for (int i = 0; i < 4; i++)
#pragma unroll
        for (int j = 0; j < 4; j++) acc[i][j] = (floatx4)0.0f;

    const short8* fAh = (const short8*)lAh;
    const short8* fAl = (const short8*)lAl;
    const short8* fBh = (const short8*)lBh;
    const short8* fBl = (const short8*)lBl;

    for (int k0 = 0; k0 < K; k0 += 32) {
        __syncthreads();
        // stage: each wave loads 2 subtiles of each of the 4 arrays.
        // subtile sf: lane l -> global row (sf*16 + (l&15)), k-chunk (l>>4)*8;
        // LDS dest linear (base + lane*16) == fragment order.
#pragma unroll
        for (int s = 0; s < 2; s++) {
            int sf = 2 * w + s;
            size_t arow = (size_t)(bm + sf * 16 + r15) * K + k0 + hq * 8;
            size_t brow = (size_t)(bn + sf * 16 + r15) * K + k0 + hq * 8;
            gload16(Ah + arow, &lAh[sf * 512]);
            gload16(Al + arow, &lAl[sf * 512]);
            gload16(Bh + brow, &lBh[sf * 512]);
            gload16(Bl + brow, &lBl[sf * 512]);
        }
        __syncthreads();

        short8 a_h[4], a_l[4], b_h[4], b_l[4];
#pragma unroll
        for (int i = 0; i < 4; i++) {
            a_h[i] = fAh[(wr * 4 + i) * 64 + lane];
            a_l[i] = fAl[(wr * 4 + i) * 64 + lane];
            b_h[i] = fBh[(wc * 4 + i) * 64 + lane];
            b_l[i] = fBl[(wc * 4 + i) * 64 + lane];
        }
#pragma unroll
        for (int i = 0; i < 4; i++)
#pragma unroll
            for (int j = 0; j < 4; j++) {
                acc[i][j] = __builtin_amdgcn_mfma_f32_16x16x32_bf16(a_h[i], b_h[j], acc[i][j], 0, 0, 0);
                acc[i][j] = __builtin_amdgcn_mfma_f32_16x16x32_bf16(a_h[i], b_l[j], acc[i][j], 0, 0, 0);
                acc[i][j] = __builtin_amdgcn_mfma_f32_16x16x32_bf16(a_l[i], b_h[j], acc[i][j], 0, 0, 0);
            }
    }

    // epilogue: C/D mapping col = lane&15, row = (lane>>4)*4 + reg
    int er = (lane >> 4) * 4, ec = lane & 15;
#pragma unroll
    for (int i = 0; i < 4; i++)
#pragma unroll
        for (int j = 0; j < 4; j++)
#pragma unroll
            for (int r = 0; r < 4; r++) {
                int row = bm + wr * 64 + i * 16 + er + r;
                int col = bn + wc * 64 + j * 16 + ec;
                float v = acc[i][j][r];
                if (EPI == 0) {
                    Cf[(size_t)row * N + col] = v;
                } else if (EPI == 1) {
                    Cf[(size_t)row * N + col] = v + R[(size_t)row * N + col];
                } else {
                    float g = gelu_f(v);
                    unsigned short hh, ll;
                    splitf(g, hh, ll);
                    Ch[(size_t)row * N + col] = hh;
                    Cl[(size_t)row * N + col] = ll;
                }
            }
}

// ---------------------------------------------------------------------------
// Flash-style causal attention, fp32 math, hi/lo bf16 output.
// ---------------------------------------------------------------------------
__global__ __launch_bounds__(256) void attn_kernel(const float* __restrict__ qkv,
                                                   unsigned short* __restrict__ yh,
                                                   unsigned short* __restrict__ yl) {
    __shared__ float Qst[HD_][68];
    __shared__ float Kst[HD_][68];
    __shared__ float Vs[64][68];
    __shared__ float Ps[64][68];

    int qt  = blockIdx.x;
    int bh  = blockIdx.y;
    int b   = bh >> 4, h = bh & 15;
    int tid = threadIdx.x;
    int tx  = tid & 15, ty = tid >> 4;
    int q0  = qt * 64;
    const float* base = qkv + (size_t)b * T_ * (3 * C_) + h * HD_;

#pragma unroll
    for (int i = 0; i < 4; i++) {
        int f   = tid * 4 + i;
        int row = f >> 4;
        int c   = (f & 15) * 4;
        float4 v = *(const float4*)(base + (size_t)(q0 + row) * (3 * C_) + c);
        Qst[c + 0][row] = v.x; Qst[c + 1][row] = v.y;
        Qst[c + 2][row] = v.z; Qst[c + 3][row] = v.w;
    }

    float m_[4], l_[4], O[4][4];
#pragma unroll
    for (int i = 0; i < 4; i++) {
        m_[i] = -INFINITY; l_[i] = 0.0f;
#pragma unroll
        for (int j = 0; j < 4; j++) O[i][j] = 0.0f;
    }

    for (int kt = 0; kt <= qt; kt++) {
        int k0 = kt * 64;
        __syncthreads();
#pragma unroll
        for (int i = 0; i < 4; i++) {
            int f   = tid * 4 + i;
            int row = f >> 4;
            int c   = (f & 15) * 4;
            float4 kv = *(const float4*)(base + C_ + (size_t)(k0 + row) * (3 * C_) + c);
            Kst[c + 0][row] = kv.x; Kst[c + 1][row] = kv.y;
            Kst[c + 2][row] = kv.z; Kst[c + 3][row] = kv.w;
            float4 vv = *(const float4*)(base + 2 * C_ + (size_t)(k0 + row) * (3 * C_) + c);
            *(float4*)(&Vs[row][c]) = vv;
        }
        __syncthreads();

        float s[4][4];
#pragma unroll
        for (int i = 0; i < 4; i++)
#pragma unroll
            for (int j = 0; j < 4; j++) s[i][j] = 0.0f;
#pragma unroll 8
        for (int d = 0; d < HD_; d++) {
            float qa[4], kb[4];
            *(float4*)qa = *(const float4*)(&Qst[d][ty * 4]);
            *(float4*)kb = *(const float4*)(&Kst[d][tx * 4]);
#pragma unroll
            for (int i = 0; i < 4; i++)
#pragma unroll
                for (int j = 0; j < 4; j++) s[i][j] += qa[i] * kb[j];
        }

        bool diag = (kt == qt);
#pragma unroll
        for (int i = 0; i < 4; i++) {
            int qg = q0 + ty * 4 + i;
            float sv[4];
#pragma unroll
            for (int j = 0; j < 4; j++) {
                float val = s[i][j] * 0.125f;
                int kg = k0 + tx * 4 + j;
                if (diag && kg > qg) val = -INFINITY;
                sv[j] = val;
            }
            float mt = fmaxf(fmaxf(sv[0], sv[1]), fmaxf(sv[2], sv[3]));
#pragma unroll
            for (int off = 1; off < 16; off <<= 1) mt = fmaxf(mt, __shfl_xor(mt, off));
            float mnew = fmaxf(m_[i], mt);
            float p[4], sum = 0.0f;
#pragma unroll
            for (int j = 0; j < 4; j++) { p[j] = __expf(sv[j] - mnew); sum += p[j]; }
#pragma unroll
            for (int off = 1; off < 16; off <<= 1) sum += __shfl_xor(sum, off);
            float alpha = __expf(m_[i] - mnew);
            l_[i] = alpha * l_[i] + sum;
            m_[i] = mnew;
#pragma unroll
            for (int j = 0; j < 4; j++) O[i][j] *= alpha;
            *(float4*)(&Ps[ty * 4 + i][tx * 4]) = make_float4(p[0], p[1], p[2], p[3]);
        }
        __syncthreads();

#pragma unroll 4
        for (int k = 0; k < 64; k++) {
            float vv[4];
            *(float4*)vv = *(const float4*)(&Vs[k][tx * 4]);
#pragma unroll
            for (int i = 0; i < 4; i++) {
                float pv = Ps[ty * 4 + i][k];
#pragma unroll
                for (int j = 0; j < 4; j++) O[i][j] += pv * vv[j];
            }
        }
    }

#pragma unroll
    for (int i = 0; i < 4; i++) {
        float inv = 1.0f / l_[i];
        int t = q0 + ty * 4 + i;
        ushort4 hv, lv;
        splitf(O[i][0] * inv, hv.x, lv.x);
        splitf(O[i][1] * inv, hv.y, lv.y);
        splitf(O[i][2] * inv, hv.z, lv.z);
        splitf(O[i][3] * inv, hv.w, lv.w);
        size_t o = (size_t)(b * T_ + t) * C_ + h * HD_ + tx * 4;
        *(ushort4*)(yh + o) = hv;
        *(ushort4*)(yl + o) = lv;
    }
}

// ---------------------------------------------------------------------------
extern "C" void kernel_launch(void* const* d_in, const int* in_sizes, int n_in,
                              void* d_out, int out_size, void* d_ws, size_t ws_size,
                              hipStream_t stream) {
    const float* x        = (const float*)d_in[0];
    const float* w_attn   = (const float*)d_in[1];
    const float* w_proj   = (const float*)d_in[2];
    const float* w_fc     = (const float*)d_in[3];
    const float* w_fcproj = (const float*)d_in[4];
    const float* ln1_w    = (const float*)d_in[5];
    const float* ln1_b    = (const float*)d_in[6];
    const float* ln2_w    = (const float*)d_in[7];
    const float* ln2_b    = (const float*)d_in[8];
    float* out = (float*)d_out;

    char* ws = (char*)d_ws;
    // act region time-shares with qkv (qkv dead after attn; act written later)
    unsigned short* act_h = (unsigned short*)(ws + 0);          // 32 MB
    unsigned short* act_l = (unsigned short*)(ws + 33554432);   // 32 MB
    float*          qkv   = (float*)(ws + 0);                   // 50 MB (overlaps act)
    float*          x1    = (float*)(ws + 67108864);            // 16 MB
    unsigned short* ln_h  = (unsigned short*)(ws + 83886080);   // 8 MB
    unsigned short* ln_l  = (unsigned short*)(ws + 92274688);   // 8 MB
    unsigned short* yb_h  = (unsigned short*)(ws + 100663296);  // 8 MB
    unsigned short* yb_l  = (unsigned short*)(ws + 109051904);  // 8 MB
    unsigned short* wat_h = (unsigned short*)(ws + 117440512);  // 6 MB [3072][1024]
    unsigned short* wat_l = (unsigned short*)(ws + 123731968);
    unsigned short* wpt_h = (unsigned short*)(ws + 130023424);  // 2 MB [1024][1024]
    unsigned short* wpt_l = (unsigned short*)(ws + 132120576);
    unsigned short* wft_h = (unsigned short*)(ws + 134217728);  // 8 MB [4096][1024]
    unsigned short* wft_l = (unsigned short*)(ws + 142606336);
    unsigned short* wfpt_h= (unsigned short*)(ws + 150994944);  // 8 MB [1024][4096]
    unsigned short* wfpt_l= (unsigned short*)(ws + 159383552);  // ends 160 MB

    // weight convert+transpose (independent of x)
    wtrans_kernel<<<dim3(48, 16), 256, 0, stream>>>(w_attn,   wat_h,  wat_l,  1024, 3072);
    wtrans_kernel<<<dim3(16, 16), 256, 0, stream>>>(w_proj,   wpt_h,  wpt_l,  1024, 1024);
    wtrans_kernel<<<dim3(64, 16), 256, 0, stream>>>(w_fc,     wft_h,  wft_l,  1024, 4096);
    wtrans_kernel<<<dim3(16, 64), 256, 0, stream>>>(w_fcproj, wfpt_h, wfpt_l, 4096, 1024);

    // 1. ln1(x) -> hi/lo
    ln_kernel<<<M_, 256, 0, stream>>>(x, ln1_w, ln1_b, ln_h, ln_l);
    // 2. qkv = ln1 @ w_attn (f32 out)
    mfma_gemm<0><<<dim3(24, 32), 256, 0, stream>>>(ln_h, ln_l, wat_h, wat_l,
                                                   nullptr, qkv, nullptr, nullptr, 3072, 1024);
    // 3. attention -> yb hi/lo
    attn_kernel<<<dim3(32, 32), 256, 0, stream>>>(qkv, yb_h, yb_l);
    // 4. x1 = yb @ w_proj + x
    mfma_gemm<1><<<dim3(8, 32), 256, 0, stream>>>(yb_h, yb_l, wpt_h, wpt_l,
                                                  x, x1, nullptr, nullptr, 1024, 1024);
    // 5. ln2(x1) -> hi/lo
    ln_kernel<<<M_, 256, 0, stream>>>(x1, ln2_w, ln2_b, ln_h, ln_l);
    // 6. act = gelu(ln2 @ w_fc) -> hi/lo
    mfma_gemm<2><<<dim3(32, 32), 256, 0, stream>>>(ln_h, ln_l, wft_h, wft_l,
                                                   nullptr, nullptr, act_h, act_l, 4096, 1024);
    // 7. out = act @ w_fcproj + x1
    mfma_gemm<1><<<dim3(8, 32), 256, 0, stream>>>(act_h, act_l, wfpt_h, wfpt_l,
                                                  x1, out, nullptr, nullptr, 1024, 4096);
}

// Round 3
// 915.735 us; speedup vs baseline: 2.2088x; 1.2839x over previous
//
#include <hip/hip_runtime.h>
#include <math.h>

#define B_   2
#define T_   2048
#define C_   1024
#define H_   16
#define HD_  64
#define M_   (B_ * T_)   // 4096

typedef __attribute__((ext_vector_type(8))) short short8;
typedef __attribute__((ext_vector_type(4))) float floatx4;
typedef __attribute__((ext_vector_type(8))) unsigned short ushort8v;

// split fp32 -> bf16 hi (RNE) + bf16 lo (RNE of remainder)
__device__ __forceinline__ void splitf(float x, unsigned short& h, unsigned short& l) {
    unsigned u  = __float_as_uint(x);
    unsigned hr = (u + 0x7fffu + ((u >> 16) & 1u)) >> 16;
    h = (unsigned short)hr;
    float r = x - __uint_as_float(hr << 16);
    unsigned ur = __float_as_uint(r);
    l = (unsigned short)((ur + 0x7fffu + ((ur >> 16) & 1u)) >> 16);
}

__device__ __forceinline__ void gload16(const void* g, void* l) {
    __builtin_amdgcn_global_load_lds(
        (const __attribute__((address_space(1))) unsigned int*)g,
        (__attribute__((address_space(3))) unsigned int*)l, 16, 0, 0);
}

__device__ __forceinline__ float gelu_f(float x) {
    const float c = 0.7978845608028654f;  // sqrt(2/pi)
    float x3 = x * x * x;
    return 0.5f * x * (1.0f + tanhf(c * (x + 0.044715f * x3)));
}

// ---------------------------------------------------------------------------
// LayerNorm: one block per row, outputs hi/lo bf16.
// ---------------------------------------------------------------------------
__global__ __launch_bounds__(256) void ln_kernel(const float* __restrict__ x,
                                                 const float* __restrict__ w,
                                                 const float* __restrict__ b,
                                                 unsigned short* __restrict__ oh,
                                                 unsigned short* __restrict__ ol) {
    int row = blockIdx.x;
    int t   = threadIdx.x;
    const float4* xr = (const float4*)(x + (size_t)row * C_);
    float4 v = xr[t];
    float s  = v.x + v.y + v.z + v.w;
    float sq = v.x * v.x + v.y * v.y + v.z * v.z + v.w * v.w;
#pragma unroll
    for (int off = 32; off > 0; off >>= 1) {
        s  += __shfl_down(s,  off);
        sq += __shfl_down(sq, off);
    }
    __shared__ float ss[4], ssq[4];
    int wid = t >> 6, lane = t & 63;
    if (lane == 0) { ss[wid] = s; ssq[wid] = sq; }
    __syncthreads();
    float S  = ss[0] + ss[1] + ss[2] + ss[3];
    float SQ = ssq[0] + ssq[1] + ssq[2] + ssq[3];
    float mu   = S * (1.0f / C_);
    float var  = SQ * (1.0f / C_) - mu * mu;
    float rstd = rsqrtf(var + 1e-5f);
    float4 wv = ((const float4*)w)[t];
    float4 bv = ((const float4*)b)[t];
    float o0 = (v.x - mu) * rstd * wv.x + bv.x;
    float o1 = (v.y - mu) * rstd * wv.y + bv.y;
    float o2 = (v.z - mu) * rstd * wv.z + bv.z;
    float o3 = (v.w - mu) * rstd * wv.w + bv.w;
    ushort4 hv, lv;
    splitf(o0, hv.x, lv.x); splitf(o1, hv.y, lv.y);
    splitf(o2, hv.z, lv.z); splitf(o3, hv.w, lv.w);
    *(ushort4*)(oh + (size_t)row * C_ + t * 4) = hv;
    *(ushort4*)(ol + (size_t)row * C_ + t * 4) = lv;
}

// ---------------------------------------------------------------------------
// Weight convert + transpose: W [K][N] f32 -> Wt_hi/lo [N][K] bf16.
// ---------------------------------------------------------------------------
__global__ __launch_bounds__(256) void wtrans_kernel(const float* __restrict__ W,
                                                     unsigned short* __restrict__ th,
                                                     unsigned short* __restrict__ tl,
                                                     int K, int N) {
    __shared__ unsigned int tile[64][65];  // hi | lo<<16
    int n0 = blockIdx.x * 64, k0 = blockIdx.y * 64;
    int t  = threadIdx.x;
    int tc = (t & 15) * 4, tr = t >> 4;
#pragma unroll
    for (int it = 0; it < 4; it++) {
        int kr = it * 16 + tr;
        float4 v = *(const float4*)(W + (size_t)(k0 + kr) * N + n0 + tc);
        unsigned short hh, ll;
        splitf(v.x, hh, ll); tile[kr][tc + 0] = (unsigned)hh | ((unsigned)ll << 16);
        splitf(v.y, hh, ll); tile[kr][tc + 1] = (unsigned)hh | ((unsigned)ll << 16);
        splitf(v.z, hh, ll); tile[kr][tc + 2] = (unsigned)hh | ((unsigned)ll << 16);
        splitf(v.w, hh, ll); tile[kr][tc + 3] = (unsigned)hh | ((unsigned)ll << 16);
    }
    __syncthreads();
    int nl = t >> 2, kc = (t & 3) * 16;
    ushort8v h0, h1, l0, l1;
#pragma unroll
    for (int e = 0; e < 8; e++) {
        unsigned u = tile[kc + e][nl];
        h0[e] = (unsigned short)(u & 0xffff); l0[e] = (unsigned short)(u >> 16);
    }
#pragma unroll
    for (int e = 0; e < 8; e++) {
        unsigned u = tile[kc + 8 + e][nl];
        h1[e] = (unsigned short)(u & 0xffff); l1[e] = (unsigned short)(u >> 16);
    }
    size_t o = (size_t)(n0 + nl) * K + k0 + kc;
    *(ushort8v*)(th + o)     = h0;
    *(ushort8v*)(th + o + 8) = h1;
    *(ushort8v*)(tl + o)     = l0;
    *(ushort8v*)(tl + o + 8) = l1;
}

// ---------------------------------------------------------------------------
// Split-bf16 MFMA GEMM: C[M,N] = A[M,K] @ B[K,N], B given transposed [N][K].
// EPI: 1 = f32 + residual; 2 = gelu -> hi/lo bf16; 3 = qkv scatter epilogue
//   (Q->(Ch,Cl)[B,H,T,64], K->(K2h,K2l)[B,H,T,64], V->(V2h,V2l)[B,H,64,T]).
// ---------------------------------------------------------------------------
template <int EPI>
__global__ __launch_bounds__(256) void mfma_gemm(
    const unsigned short* __restrict__ Ah, const unsigned short* __restrict__ Al,
    const unsigned short* __restrict__ Bh, const unsigned short* __restrict__ Bl,
    const float* __restrict__ R, float* __restrict__ Cf,
    unsigned short* __restrict__ Ch, unsigned short* __restrict__ Cl,
    unsigned short* __restrict__ K2h, unsigned short* __restrict__ K2l,
    unsigned short* __restrict__ V2h, unsigned short* __restrict__ V2l,
    int N, int K) {
    __shared__ unsigned short lAh[128 * 32], lAl[128 * 32];
    __shared__ unsigned short lBh[128 * 32], lBl[128 * 32];
    int tid = threadIdx.x, lane = tid & 63, w = tid >> 6;
    int wr = w >> 1, wc = w & 1;
    int bm = blockIdx.y * 128, bn = blockIdx.x * 128;
    int r15 = lane & 15, hq = lane >> 4;

    floatx4 acc[4][4];
#pragma unroll
    for (int i = 0; i < 4; i++)
#pragma unroll
        for (int j = 0; j < 4; j++) acc[i][j] = (floatx4)0.0f;

    const short8* fAh = (const short8*)lAh;
    const short8* fAl = (const short8*)lAl;
    const short8* fBh = (const short8*)lBh;
    const short8* fBl = (const short8*)lBl;

    for (int k0 = 0; k0 < K; k0 += 32) {
        __syncthreads();
#pragma unroll
        for (int s = 0; s < 2; s++) {
            int sf = 2 * w + s;
            size_t arow = (size_t)(bm + sf * 16 + r15) * K + k0 + hq * 8;
            size_t brow = (size_t)(bn + sf * 16 + r15) * K + k0 + hq * 8;
            gload16(Ah + arow, &lAh[sf * 512]);
            gload16(Al + arow, &lAl[sf * 512]);
            gload16(Bh + brow, &lBh[sf * 512]);
            gload16(Bl + brow, &lBl[sf * 512]);
        }
        __syncthreads();

        short8 a_h[4], a_l[4], b_h[4], b_l[4];
#pragma unroll
        for (int i = 0; i < 4; i++) {
            a_h[i] = fAh[(wr * 4 + i) * 64 + lane];
            a_l[i] = fAl[(wr * 4 + i) * 64 + lane];
            b_h[i] = fBh[(wc * 4 + i) * 64 + lane];
            b_l[i] = fBl[(wc * 4 + i) * 64 + lane];
        }
#pragma unroll
        for (int i = 0; i < 4; i++)
#pragma unroll
            for (int j = 0; j < 4; j++) {
                acc[i][j] = __builtin_amdgcn_mfma_f32_16x16x32_bf16(a_h[i], b_h[j], acc[i][j], 0, 0, 0);
                acc[i][j] = __builtin_amdgcn_mfma_f32_16x16x32_bf16(a_h[i], b_l[j], acc[i][j], 0, 0, 0);
                acc[i][j] = __builtin_amdgcn_mfma_f32_16x16x32_bf16(a_l[i], b_h[j], acc[i][j], 0, 0, 0);
            }
    }

    int er = hq * 4, ec = r15;
#pragma unroll
    for (int i = 0; i < 4; i++) {
#pragma unroll
        for (int j = 0; j < 4; j++) {
            int row0 = bm + wr * 64 + i * 16 + er;
            int col  = bn + wc * 64 + j * 16 + ec;
            if (EPI == 1) {
#pragma unroll
                for (int r = 0; r < 4; r++) {
                    int row = row0 + r;
                    Cf[(size_t)row * N + col] = acc[i][j][r] + R[(size_t)row * N + col];
                }
            } else if (EPI == 2) {
#pragma unroll
                for (int r = 0; r < 4; r++) {
                    int row = row0 + r;
                    float g = gelu_f(acc[i][j][r]);
                    unsigned short hh, ll;
                    splitf(g, hh, ll);
                    Ch[(size_t)row * N + col] = hh;
                    Cl[(size_t)row * N + col] = ll;
                }
            } else {  // EPI == 3: qkv scatter
                int region = bn >> 10;           // uniform per block
                int b_ = row0 >> 11;
                int h_ = (col >> 6) & 15;
                int d_ = col & 63;
                size_t bh_ = (size_t)(b_ * 16 + h_);
                if (region == 2) {
                    ushort4 hv, lv;
                    splitf(acc[i][j][0], hv.x, lv.x);
                    splitf(acc[i][j][1], hv.y, lv.y);
                    splitf(acc[i][j][2], hv.z, lv.z);
                    splitf(acc[i][j][3], hv.w, lv.w);
                    size_t o = (bh_ * 64 + d_) * 2048 + (row0 & 2047);
                    *(ushort4*)(V2h + o) = hv;
                    *(ushort4*)(V2l + o) = lv;
                } else {
                    unsigned short* dh = (region == 0) ? Ch : K2h;
                    unsigned short* dl = (region == 0) ? Cl : K2l;
#pragma unroll
                    for (int r = 0; r < 4; r++) {
                        int t = (row0 + r) & 2047;
                        unsigned short hh, ll;
                        splitf(acc[i][j][r], hh, ll);
                        size_t o = (bh_ * 2048 + t) * 64 + d_;
                        dh[o] = hh;
                        dl[o] = ll;
                    }
                }
            }
        }
    }
}

// ---------------------------------------------------------------------------
// Split-bf16 MFMA flash attention (causal). Q-tile 64 rows/block, 4 waves x
// 16 rows, KV-tile 64. Q [B,H,T,64] hi/lo, K [B,H,T,64] hi/lo,
// V [B,H,64,T] hi/lo (transposed). Output y [B,T,C] hi/lo bf16.
// ---------------------------------------------------------------------------
__global__ __launch_bounds__(256) void attn_mfma(
    const unsigned short* __restrict__ Qh_g, const unsigned short* __restrict__ Ql_g,
    const unsigned short* __restrict__ Kh_g, const unsigned short* __restrict__ Kl_g,
    const unsigned short* __restrict__ Vh_g, const unsigned short* __restrict__ Vl_g,
    unsigned short* __restrict__ yh, unsigned short* __restrict__ yl) {
    __shared__ unsigned short Ks_h[4096], Ks_l[4096], Vs_h[4096], Vs_l[4096];
    __shared__ unsigned short P_s[4][2][1024];  // wave-private 16x64, XOR-swizzled

    int qt  = (int)(gridDim.x - 1) - (int)blockIdx.x;  // heavy tiles first
    int bh  = blockIdx.y;
    int b   = bh >> 4, h = bh & 15;
    int tid = threadIdx.x, lane = tid & 63, w = tid >> 6;
    int r15 = lane & 15, hq = lane >> 4;
    int q0  = qt * 64;
    size_t bhq = (size_t)bh * (2048 * 64);   // Q/K base (elements)
    size_t bhv = (size_t)bh * (64 * 2048);   // V^T base

    // Q fragments in registers (rows w*16+r15, d-chunks 0/1)
    short8 qfh[2], qfl[2];
    {
        size_t base = bhq + (size_t)(q0 + w * 16 + r15) * 64 + hq * 8;
        qfh[0] = *(const short8*)(Qh_g + base);
        qfh[1] = *(const short8*)(Qh_g + base + 32);
        qfl[0] = *(const short8*)(Ql_g + base);
        qfl[1] = *(const short8*)(Ql_g + base + 32);
    }

    floatx4 O[4];
    float m_[4], l_[4];
#pragma unroll
    for (int j = 0; j < 4; j++) O[j] = (floatx4)0.0f;
#pragma unroll
    for (int r = 0; r < 4; r++) { m_[r] = -INFINITY; l_[r] = 0.0f; }

    const short8* fKh = (const short8*)Ks_h;
    const short8* fKl = (const short8*)Ks_l;
    const short8* fVh = (const short8*)Vs_h;
    const short8* fVl = (const short8*)Vs_l;

    for (int kt = 0; kt <= qt; kt++) {
        int k0 = kt * 64;
        __syncthreads();
        // stage K (frag-order [kvblk][dchunk]) and V^T ([dblk][kvchunk])
#pragma unroll
        for (int s = 0; s < 2; s++) {
            int sf = 2 * w + s;
            int rb = sf >> 1, cb = sf & 1;
            size_t koff = bhq + (size_t)(k0 + rb * 16 + r15) * 64 + cb * 32 + hq * 8;
            size_t voff = bhv + (size_t)(rb * 16 + r15) * 2048 + k0 + cb * 32 + hq * 8;
            gload16(Kh_g + koff, &Ks_h[sf * 512]);
            gload16(Kl_g + koff, &Ks_l[sf * 512]);
            gload16(Vh_g + voff, &Vs_h[sf * 512]);
            gload16(Vl_g + voff, &Vs_l[sf * 512]);
        }
        __syncthreads();

        // S = Q K^T : frag j covers kv cols k0 + j*16 ..
        floatx4 S[4];
#pragma unroll
        for (int j = 0; j < 4; j++) {
            short8 kh0 = fKh[(j * 2 + 0) * 64 + lane];
            short8 kh1 = fKh[(j * 2 + 1) * 64 + lane];
            short8 kl0 = fKl[(j * 2 + 0) * 64 + lane];
            short8 kl1 = fKl[(j * 2 + 1) * 64 + lane];
            floatx4 a = (floatx4)0.0f;
            a = __builtin_amdgcn_mfma_f32_16x16x32_bf16(qfh[0], kh0, a, 0, 0, 0);
            a = __builtin_amdgcn_mfma_f32_16x16x32_bf16(qfh[1], kh1, a, 0, 0, 0);
            a = __builtin_amdgcn_mfma_f32_16x16x32_bf16(qfh[0], kl0, a, 0, 0, 0);
            a = __builtin_amdgcn_mfma_f32_16x16x32_bf16(qfh[1], kl1, a, 0, 0, 0);
            a = __builtin_amdgcn_mfma_f32_16x16x32_bf16(qfl[0], kh0, a, 0, 0, 0);
            a = __builtin_amdgcn_mfma_f32_16x16x32_bf16(qfl[1], kh1, a, 0, 0, 0);
            S[j] = a;
        }

        // scale + causal mask
        bool diag = (kt == qt);
#pragma unroll
        for (int j = 0; j < 4; j++)
#pragma unroll
            for (int r = 0; r < 4; r++) {
                float v = S[j][r] * 0.125f;
                if (diag && (k0 + j * 16 + r15) > (q0 + w * 16 + hq * 4 + r)) v = -INFINITY;
                S[j][r] = v;
            }

        // online softmax (row-reduce across the 16-lane col group)
        float alpha[4];
#pragma unroll
        for (int r = 0; r < 4; r++) {
            float mt = fmaxf(fmaxf(S[0][r], S[1][r]), fmaxf(S[2][r], S[3][r]));
#pragma unroll
            for (int off = 1; off < 16; off <<= 1) mt = fmaxf(mt, __shfl_xor(mt, off));
            float mn = fmaxf(m_[r], mt);
            alpha[r] = __expf(m_[r] - mn);
            m_[r] = mn;
        }
        float rowsum[4] = {0.f, 0.f, 0.f, 0.f};
#pragma unroll
        for (int j = 0; j < 4; j++)
#pragma unroll
            for (int r = 0; r < 4; r++) {
                float p = __expf(S[j][r] - m_[r]);
                S[j][r] = p;
                rowsum[r] += p;
            }
#pragma unroll
        for (int r = 0; r < 4; r++) {
#pragma unroll
            for (int off = 1; off < 16; off <<= 1) rowsum[r] += __shfl_xor(rowsum[r], off);
            l_[r] = l_[r] * alpha[r] + rowsum[r];
        }
        // rescale O
#pragma unroll
        for (int jd = 0; jd < 4; jd++)
#pragma unroll
            for (int r = 0; r < 4; r++) O[jd][r] *= alpha[r];

        // P (D-layout) -> LDS (A-layout, XOR-swizzled), split hi/lo
        char* pw0 = (char*)&P_s[w][0][0];
        char* pw1 = (char*)&P_s[w][1][0];
#pragma unroll
        for (int j = 0; j < 4; j++)
#pragma unroll
            for (int r = 0; r < 4; r++) {
                int prow = hq * 4 + r;
                unsigned byte = (unsigned)(prow * 128 + (j * 16 + r15) * 2) ^ ((prow & 7) << 4);
                unsigned short ph, pl;
                splitf(S[j][r], ph, pl);
                *(unsigned short*)(pw0 + byte) = ph;
                *(unsigned short*)(pw1 + byte) = pl;
            }
        // read back as A-frags (wave-private; compiler orders LDS ops)
        short8 pah[2], pal[2];
#pragma unroll
        for (int c = 0; c < 2; c++) {
            unsigned byte = (unsigned)(r15 * 128 + c * 64 + hq * 16) ^ ((r15 & 7) << 4);
            pah[c] = *(const short8*)(pw0 + byte);
            pal[c] = *(const short8*)(pw1 + byte);
        }

        // O += P V
#pragma unroll
        for (int jd = 0; jd < 4; jd++) {
            short8 vh0 = fVh[(jd * 2 + 0) * 64 + lane];
            short8 vh1 = fVh[(jd * 2 + 1) * 64 + lane];
            short8 vl0 = fVl[(jd * 2 + 0) * 64 + lane];
            short8 vl1 = fVl[(jd * 2 + 1) * 64 + lane];
            floatx4 a = O[jd];
            a = __builtin_amdgcn_mfma_f32_16x16x32_bf16(pah[0], vh0, a, 0, 0, 0);
            a = __builtin_amdgcn_mfma_f32_16x16x32_bf16(pah[1], vh1, a, 0, 0, 0);
            a = __builtin_amdgcn_mfma_f32_16x16x32_bf16(pah[0], vl0, a, 0, 0, 0);
            a = __builtin_amdgcn_mfma_f32_16x16x32_bf16(pah[1], vl1, a, 0, 0, 0);
            a = __builtin_amdgcn_mfma_f32_16x16x32_bf16(pal[0], vh0, a, 0, 0, 0);
            a = __builtin_amdgcn_mfma_f32_16x16x32_bf16(pal[1], vh1, a, 0, 0, 0);
            O[jd] = a;
        }
    }

    // normalize + write y hi/lo
#pragma unroll
    for (int r = 0; r < 4; r++) l_[r] = 1.0f / l_[r];
#pragma unroll
    for (int jd = 0; jd < 4; jd++)
#pragma unroll
        for (int r = 0; r < 4; r++) {
            int t   = q0 + w * 16 + hq * 4 + r;
            int col = h * 64 + jd * 16 + r15;
            float v = O[jd][r] * l_[r];
            unsigned short hh, ll;
            splitf(v, hh, ll);
            size_t o = ((size_t)b * 2048 + t) * 1024 + col;
            yh[o] = hh;
            yl[o] = ll;
        }
}

// ---------------------------------------------------------------------------
extern "C" void kernel_launch(void* const* d_in, const int* in_sizes, int n_in,
                              void* d_out, int out_size, void* d_ws, size_t ws_size,
                              hipStream_t stream) {
    const float* x        = (const float*)d_in[0];
    const float* w_attn   = (const float*)d_in[1];
    const float* w_proj   = (const float*)d_in[2];
    const float* w_fc     = (const float*)d_in[3];
    const float* w_fcproj = (const float*)d_in[4];
    const float* ln1_w    = (const float*)d_in[5];
    const float* ln1_b    = (const float*)d_in[6];
    const float* ln2_w    = (const float*)d_in[7];
    const float* ln2_b    = (const float*)d_in[8];
    float* out = (float*)d_out;

    char* ws = (char*)d_ws;
    const size_t MB = 1048576;
    unsigned short* Qh   = (unsigned short*)(ws + 0 * MB);    // 8 MB each
    unsigned short* Ql   = (unsigned short*)(ws + 8 * MB);
    unsigned short* Kh   = (unsigned short*)(ws + 16 * MB);
    unsigned short* Kl   = (unsigned short*)(ws + 24 * MB);
    unsigned short* Vth  = (unsigned short*)(ws + 32 * MB);
    unsigned short* Vtl  = (unsigned short*)(ws + 40 * MB);
    unsigned short* acth = (unsigned short*)(ws + 0 * MB);    // 32 MB, reuses Q/K
    unsigned short* actl = (unsigned short*)(ws + 32 * MB);   // 32 MB, reuses Vt
    float*          x1   = (float*)(ws + 64 * MB);            // 16 MB
    unsigned short* ln_h = (unsigned short*)(ws + 80 * MB);
    unsigned short* ln_l = (unsigned short*)(ws + 88 * MB);
    unsigned short* yb_h = (unsigned short*)(ws + 96 * MB);
    unsigned short* yb_l = (unsigned short*)(ws + 104 * MB);
    unsigned short* wat_h  = (unsigned short*)(ws + 112 * MB);  // 6 MB
    unsigned short* wat_l  = (unsigned short*)(ws + 118 * MB);
    unsigned short* wpt_h  = (unsigned short*)(ws + 124 * MB);  // 2 MB
    unsigned short* wpt_l  = (unsigned short*)(ws + 126 * MB);
    unsigned short* wft_h  = (unsigned short*)(ws + 128 * MB);  // 8 MB
    unsigned short* wft_l  = (unsigned short*)(ws + 136 * MB);
    unsigned short* wfpt_h = (unsigned short*)(ws + 144 * MB);  // 8 MB
    unsigned short* wfpt_l = (unsigned short*)(ws + 152 * MB);  // ends 160 MB

    // weight convert+transpose
    wtrans_kernel<<<dim3(48, 16), 256, 0, stream>>>(w_attn,   wat_h,  wat_l,  1024, 3072);
    wtrans_kernel<<<dim3(16, 16), 256, 0, stream>>>(w_proj,   wpt_h,  wpt_l,  1024, 1024);
    wtrans_kernel<<<dim3(64, 16), 256, 0, stream>>>(w_fc,     wft_h,  wft_l,  1024, 4096);
    wtrans_kernel<<<dim3(16, 64), 256, 0, stream>>>(w_fcproj, wfpt_h, wfpt_l, 4096, 1024);

    // 1. ln1(x)
    ln_kernel<<<M_, 256, 0, stream>>>(x, ln1_w, ln1_b, ln_h, ln_l);
    // 2. qkv GEMM with scatter epilogue -> Q,K,[B,H,T,64]; V^T [B,H,64,T]
    mfma_gemm<3><<<dim3(24, 32), 256, 0, stream>>>(
        ln_h, ln_l, wat_h, wat_l, nullptr, nullptr,
        Qh, Ql, Kh, Kl, Vth, Vtl, 3072, 1024);
    // 3. MFMA flash attention -> yb hi/lo
    attn_mfma<<<dim3(32, 32), 256, 0, stream>>>(Qh, Ql, Kh, Kl, Vth, Vtl, yb_h, yb_l);
    // 4. x1 = yb @ w_proj + x
    mfma_gemm<1><<<dim3(8, 32), 256, 0, stream>>>(
        yb_h, yb_l, wpt_h, wpt_l, x, x1,
        nullptr, nullptr, nullptr, nullptr, nullptr, nullptr, 1024, 1024);
    // 5. ln2(x1)
    ln_kernel<<<M_, 256, 0, stream>>>(x1, ln2_w, ln2_b, ln_h, ln_l);
    // 6. act = gelu(ln2 @ w_fc)
    mfma_gemm<2><<<dim3(32, 32), 256, 0, stream>>>(
        ln_h, ln_l, wft_h, wft_l, nullptr, nullptr,
        acth, actl, nullptr, nullptr, nullptr, nullptr, 4096, 1024);
    // 7. out = act @ w_fcproj + x1
    mfma_gemm<1><<<dim3(8, 32), 256, 0, stream>>>(
        acth, actl, wfpt_h, wfpt_l, x1, out,
        nullptr, nullptr, nullptr, nullptr, nullptr, nullptr, 1024, 4096);
}

// Round 4
// 756.492 us; speedup vs baseline: 2.6737x; 1.2105x over previous
//
#include <hip/hip_runtime.h>
#include <math.h>

#define B_   2
#define T_   2048
#define C_   1024
#define H_   16
#define HD_  64
#define M_   (B_ * T_)   // 4096

typedef __attribute__((ext_vector_type(8))) short short8;
typedef __attribute__((ext_vector_type(4))) float floatx4;
typedef __attribute__((ext_vector_type(8))) unsigned short ushort8v;

// split fp32 -> bf16 hi (RNE) + bf16 lo (RNE of remainder)
__device__ __forceinline__ void splitf(float x, unsigned short& h, unsigned short& l) {
    unsigned u  = __float_as_uint(x);
    unsigned hr = (u + 0x7fffu + ((u >> 16) & 1u)) >> 16;
    h = (unsigned short)hr;
    float r = x - __uint_as_float(hr << 16);
    unsigned ur = __float_as_uint(r);
    l = (unsigned short)((ur + 0x7fffu + ((ur >> 16) & 1u)) >> 16);
}

__device__ __forceinline__ void gload16(const void* g, void* l) {
    __builtin_amdgcn_global_load_lds(
        (const __attribute__((address_space(1))) unsigned int*)g,
        (__attribute__((address_space(3))) unsigned int*)l, 16, 0, 0);
}

__device__ __forceinline__ float gelu_f(float x) {
    const float c = 0.7978845608028654f;  // sqrt(2/pi)
    float x3 = x * x * x;
    return 0.5f * x * (1.0f + tanhf(c * (x + 0.044715f * x3)));
}

// ---------------------------------------------------------------------------
// LayerNorm: one block per row, outputs hi/lo bf16.
// ---------------------------------------------------------------------------
__global__ __launch_bounds__(256) void ln_kernel(const float* __restrict__ x,
                                                 const float* __restrict__ w,
                                                 const float* __restrict__ b,
                                                 unsigned short* __restrict__ oh,
                                                 unsigned short* __restrict__ ol) {
    int row = blockIdx.x;
    int t   = threadIdx.x;
    const float4* xr = (const float4*)(x + (size_t)row * C_);
    float4 v = xr[t];
    float s  = v.x + v.y + v.z + v.w;
    float sq = v.x * v.x + v.y * v.y + v.z * v.z + v.w * v.w;
#pragma unroll
    for (int off = 32; off > 0; off >>= 1) {
        s  += __shfl_down(s,  off);
        sq += __shfl_down(sq, off);
    }
    __shared__ float ss[4], ssq[4];
    int wid = t >> 6, lane = t & 63;
    if (lane == 0) { ss[wid] = s; ssq[wid] = sq; }
    __syncthreads();
    float S  = ss[0] + ss[1] + ss[2] + ss[3];
    float SQ = ssq[0] + ssq[1] + ssq[2] + ssq[3];
    float mu   = S * (1.0f / C_);
    float var  = SQ * (1.0f / C_) - mu * mu;
    float rstd = rsqrtf(var + 1e-5f);
    float4 wv = ((const float4*)w)[t];
    float4 bv = ((const float4*)b)[t];
    float o0 = (v.x - mu) * rstd * wv.x + bv.x;
    float o1 = (v.y - mu) * rstd * wv.y + bv.y;
    float o2 = (v.z - mu) * rstd * wv.z + bv.z;
    float o3 = (v.w - mu) * rstd * wv.w + bv.w;
    ushort4 hv, lv;
    splitf(o0, hv.x, lv.x); splitf(o1, hv.y, lv.y);
    splitf(o2, hv.z, lv.z); splitf(o3, hv.w, lv.w);
    *(ushort4*)(oh + (size_t)row * C_ + t * 4) = hv;
    *(ushort4*)(ol + (size_t)row * C_ + t * 4) = lv;
}

// ---------------------------------------------------------------------------
// Weight convert + transpose: W [K][N] f32 -> Wt_hi/lo [N][K] bf16.
// ---------------------------------------------------------------------------
__global__ __launch_bounds__(256) void wtrans_kernel(const float* __restrict__ W,
                                                     unsigned short* __restrict__ th,
                                                     unsigned short* __restrict__ tl,
                                                     int K, int N) {
    __shared__ unsigned int tile[64][65];  // hi | lo<<16
    int n0 = blockIdx.x * 64, k0 = blockIdx.y * 64;
    int t  = threadIdx.x;
    int tc = (t & 15) * 4, tr = t >> 4;
#pragma unroll
    for (int it = 0; it < 4; it++) {
        int kr = it * 16 + tr;
        float4 v = *(const float4*)(W + (size_t)(k0 + kr) * N + n0 + tc);
        unsigned short hh, ll;
        splitf(v.x, hh, ll); tile[kr][tc + 0] = (unsigned)hh | ((unsigned)ll << 16);
        splitf(v.y, hh, ll); tile[kr][tc + 1] = (unsigned)hh | ((unsigned)ll << 16);
        splitf(v.z, hh, ll); tile[kr][tc + 2] = (unsigned)hh | ((unsigned)ll << 16);
        splitf(v.w, hh, ll); tile[kr][tc + 3] = (unsigned)hh | ((unsigned)ll << 16);
    }
    __syncthreads();
    int nl = t >> 2, kc = (t & 3) * 16;
    ushort8v h0, h1, l0, l1;
#pragma unroll
    for (int e = 0; e < 8; e++) {
        unsigned u = tile[kc + e][nl];
        h0[e] = (unsigned short)(u & 0xffff); l0[e] = (unsigned short)(u >> 16);
    }
#pragma unroll
    for (int e = 0; e < 8; e++) {
        unsigned u = tile[kc + 8 + e][nl];
        h1[e] = (unsigned short)(u & 0xffff); l1[e] = (unsigned short)(u >> 16);
    }
    size_t o = (size_t)(n0 + nl) * K + k0 + kc;
    *(ushort8v*)(th + o)     = h0;
    *(ushort8v*)(th + o + 8) = h1;
    *(ushort8v*)(tl + o)     = l0;
    *(ushort8v*)(tl + o + 8) = l1;
}

// ---------------------------------------------------------------------------
// Split-bf16 MFMA GEMM, 2-phase prefetch (double-buffered LDS), XCD swizzle.
// C[M,N] = A[M,K] @ B[K,N], B transposed [N][Kstride].
// K = per-dispatch loop length; blockIdx.z selects a K-split slice
// (k_base = z*K, partial C at Cf + z*M*N).
// EPI: 0 = f32 store (split-K partial); 1 = f32 + residual;
//      2 = gelu -> hi/lo bf16; 3 = qkv scatter.
// ---------------------------------------------------------------------------
template <int EPI>
__global__ __launch_bounds__(256) void mfma_gemm(
    const unsigned short* __restrict__ Ah, const unsigned short* __restrict__ Al,
    const unsigned short* __restrict__ Bh, const unsigned short* __restrict__ Bl,
    const float* __restrict__ R, float* __restrict__ Cf,
    unsigned short* __restrict__ Ch, unsigned short* __restrict__ Cl,
    unsigned short* __restrict__ K2h, unsigned short* __restrict__ K2l,
    unsigned short* __restrict__ V2h, unsigned short* __restrict__ V2l,
    int N, int K, int Kstride) {
    __shared__ unsigned short lAh[2][4096], lAl[2][4096];
    __shared__ unsigned short lBh[2][4096], lBl[2][4096];
    int tid = threadIdx.x, lane = tid & 63, w = tid >> 6;
    int wr = w >> 1, wc = w & 1;

    // XCD-aware bijective swizzle (all grids are multiples of 8 blocks)
    int nx = gridDim.x;
    int nwg = nx * gridDim.y;
    int bid = blockIdx.y * nx + blockIdx.x;
    int q8  = nwg >> 3;
    int swz = (bid & 7) * q8 + (bid >> 3);
    int bm = (swz / nx) * 128, bn = (swz % nx) * 128;

    int kb = blockIdx.z * K;              // K-split base
    if (EPI == 0) Cf += (size_t)blockIdx.z * (size_t)gridDim.y * 128 * N;

    int r15 = lane & 15, hq = lane >> 4;

    floatx4 acc[4][4];
#pragma unroll
    for (int i = 0; i < 4; i++)
#pragma unroll
        for (int j = 0; j < 4; j++) acc[i][j] = (floatx4)0.0f;

    auto STAGE = [&](int buf, int k0) {
#pragma unroll
        for (int s = 0; s < 2; s++) {
            int sf = 2 * w + s;
            size_t arow = (size_t)(bm + sf * 16 + r15) * Kstride + kb + k0 + hq * 8;
            size_t brow = (size_t)(bn + sf * 16 + r15) * Kstride + kb + k0 + hq * 8;
            gload16(Ah + arow, &lAh[buf][sf * 512]);
            gload16(Al + arow, &lAl[buf][sf * 512]);
            gload16(Bh + brow, &lBh[buf][sf * 512]);
            gload16(Bl + brow, &lBl[buf][sf * 512]);
        }
    };

    STAGE(0, 0);
    __syncthreads();                       // drains vmcnt: tile 0 ready
    int cur = 0;
    int nt = K / 32;
    for (int t = 0; t < nt; t++) {
        if (t + 1 < nt) STAGE(cur ^ 1, (t + 1) * 32);  // prefetch next tile
        const short8* fAh = (const short8*)&lAh[cur][0];
        const short8* fAl = (const short8*)&lAl[cur][0];
        const short8* fBh = (const short8*)&lBh[cur][0];
        const short8* fBl = (const short8*)&lBl[cur][0];
        short8 a_h[4], a_l[4], b_h[4], b_l[4];
#pragma unroll
        for (int i = 0; i < 4; i++) {
            a_h[i] = fAh[(wr * 4 + i) * 64 + lane];
            a_l[i] = fAl[(wr * 4 + i) * 64 + lane];
            b_h[i] = fBh[(wc * 4 + i) * 64 + lane];
            b_l[i] = fBl[(wc * 4 + i) * 64 + lane];
        }
#pragma unroll
        for (int i = 0; i < 4; i++)
#pragma unroll
            for (int j = 0; j < 4; j++) {
                acc[i][j] = __builtin_amdgcn_mfma_f32_16x16x32_bf16(a_h[i], b_h[j], acc[i][j], 0, 0, 0);
                acc[i][j] = __builtin_amdgcn_mfma_f32_16x16x32_bf16(a_h[i], b_l[j], acc[i][j], 0, 0, 0);
                acc[i][j] = __builtin_amdgcn_mfma_f32_16x16x32_bf16(a_l[i], b_h[j], acc[i][j], 0, 0, 0);
            }
        __syncthreads();                   // drains vmcnt (next tile) + lgkm
        cur ^= 1;
    }

    int er = hq * 4, ec = r15;
#pragma unroll
    for (int i = 0; i < 4; i++) {
#pragma unroll
        for (int j = 0; j < 4; j++) {
            int row0 = bm + wr * 64 + i * 16 + er;
            int col  = bn + wc * 64 + j * 16 + ec;
            if (EPI == 0) {
#pragma unroll
                for (int r = 0; r < 4; r++)
                    Cf[(size_t)(row0 + r) * N + col] = acc[i][j][r];
            } else if (EPI == 1) {
#pragma unroll
                for (int r = 0; r < 4; r++) {
                    int row = row0 + r;
                    Cf[(size_t)row * N + col] = acc[i][j][r] + R[(size_t)row * N + col];
                }
            } else if (EPI == 2) {
#pragma unroll
                for (int r = 0; r < 4; r++) {
                    int row = row0 + r;
                    float g = gelu_f(acc[i][j][r]);
                    unsigned short hh, ll;
                    splitf(g, hh, ll);
                    Ch[(size_t)row * N + col] = hh;
                    Cl[(size_t)row * N + col] = ll;
                }
            } else {  // EPI == 3: qkv scatter
                int region = bn >> 10;           // uniform per block
                int b_ = row0 >> 11;
                int h_ = (col >> 6) & 15;
                int d_ = col & 63;
                size_t bh_ = (size_t)(b_ * 16 + h_);
                if (region == 2) {
                    ushort4 hv, lv;
                    splitf(acc[i][j][0], hv.x, lv.x);
                    splitf(acc[i][j][1], hv.y, lv.y);
                    splitf(acc[i][j][2], hv.z, lv.z);
                    splitf(acc[i][j][3], hv.w, lv.w);
                    size_t o = (bh_ * 64 + d_) * 2048 + (row0 & 2047);
                    *(ushort4*)(V2h + o) = hv;
                    *(ushort4*)(V2l + o) = lv;
                } else {
                    unsigned short* dh = (region == 0) ? Ch : K2h;
                    unsigned short* dl = (region == 0) ? Cl : K2l;
#pragma unroll
                    for (int r = 0; r < 4; r++) {
                        int t_ = (row0 + r) & 2047;
                        unsigned short hh, ll;
                        splitf(acc[i][j][r], hh, ll);
                        size_t o = (bh_ * 2048 + t_) * 64 + d_;
                        dh[o] = hh;
                        dl[o] = ll;
                    }
                }
            }
        }
    }
}

// ---------------------------------------------------------------------------
// split-K combine: out = p0 + p1 + residual
// ---------------------------------------------------------------------------
__global__ __launch_bounds__(256) void combine_kernel(const float* __restrict__ p0,
                                                      const float* __restrict__ p1,
                                                      const float* __restrict__ r,
                                                      float* __restrict__ out) {
    int i = blockIdx.x * 256 + threadIdx.x;
    float4 a = ((const float4*)p0)[i];
    float4 b = ((const float4*)p1)[i];
    float4 c = ((const float4*)r)[i];
    float4 o;
    o.x = a.x + b.x + c.x; o.y = a.y + b.y + c.y;
    o.z = a.z + b.z + c.z; o.w = a.w + b.w + c.w;
    ((float4*)out)[i] = o;
}

// ---------------------------------------------------------------------------
// Split-bf16 MFMA flash attention (causal). Q-tile 128 rows/block, 8 waves x
// 16 rows, KV-tile 64. Q,K [B,H,T,64] hi/lo, V [B,H,64,T] hi/lo (transposed).
// Output y [B,T,C] hi/lo bf16. Heavy diagonal blocks dispatched first.
// ---------------------------------------------------------------------------
__global__ __launch_bounds__(512) void attn_mfma(
    const unsigned short* __restrict__ Qh_g, const unsigned short* __restrict__ Ql_g,
    const unsigned short* __restrict__ Kh_g, const unsigned short* __restrict__ Kl_g,
    const unsigned short* __restrict__ Vh_g, const unsigned short* __restrict__ Vl_g,
    unsigned short* __restrict__ yh, unsigned short* __restrict__ yl) {
    __shared__ unsigned short Ks_h[4096], Ks_l[4096], Vs_h[4096], Vs_l[4096];  // 32 KB
    __shared__ unsigned short P_s[8][2][1024];  // per-wave 16x64 hi/lo, swizzled; 32 KB

    int qt  = 15 - (int)blockIdx.x;  // heavy tiles first
    int bh  = blockIdx.y;
    int b   = bh >> 4, h = bh & 15;
    int tid = threadIdx.x, lane = tid & 63, w = tid >> 6;   // w in 0..7
    int r15 = lane & 15, hq = lane >> 4;
    int q0  = qt * 128;
    int qrow_base = q0 + w * 16;
    size_t bhq = (size_t)bh * (2048 * 64);   // Q/K base (elements)
    size_t bhv = (size_t)bh * (64 * 2048);   // V^T base

    // Q fragments in registers (rows qrow_base + r15, d-chunks 0/1)
    short8 qfh[2], qfl[2];
    {
        size_t base = bhq + (size_t)(qrow_base + r15) * 64 + hq * 8;
        qfh[0] = *(const short8*)(Qh_g + base);
        qfh[1] = *(const short8*)(Qh_g + base + 32);
        qfl[0] = *(const short8*)(Ql_g + base);
        qfl[1] = *(const short8*)(Ql_g + base + 32);
    }

    floatx4 O[4];
    float m_[4], l_[4];
#pragma unroll
    for (int j = 0; j < 4; j++) O[j] = (floatx4)0.0f;
#pragma unroll
    for (int r = 0; r < 4; r++) { m_[r] = -INFINITY; l_[r] = 0.0f; }

    const short8* fKh = (const short8*)Ks_h;
    const short8* fKl = (const short8*)Ks_l;
    const short8* fVh = (const short8*)Vs_h;
    const short8* fVl = (const short8*)Vs_l;

    int ktmax = 2 * qt + 1;
    int srb = w >> 1, scb = w & 1;   // this wave's staging subtile coords
    for (int kt = 0; kt <= ktmax; kt++) {
        int k0 = kt * 64;
        __syncthreads();   // all waves done reading previous K/V
        {
            size_t koff = bhq + (size_t)(k0 + srb * 16 + r15) * 64 + scb * 32 + hq * 8;
            size_t voff = bhv + (size_t)(srb * 16 + r15) * 2048 + k0 + scb * 32 + hq * 8;
            gload16(Kh_g + koff, &Ks_h[w * 512]);
            gload16(Kl_g + koff, &Ks_l[w * 512]);
            gload16(Vh_g + voff, &Vs_h[w * 512]);
            gload16(Vl_g + voff, &Vs_l[w * 512]);
        }
        __syncthreads();   // K/V tile ready

        bool active = (k0 <= qrow_base + 15);
        if (!active) continue;   // fully masked for this wave (barriers already passed)
        bool needmask = (k0 + 63 > qrow_base);

        // S = Q K^T : frag j covers kv cols k0 + j*16 ..
        floatx4 S[4];
#pragma unroll
        for (int j = 0; j < 4; j++) {
            short8 kh0 = fKh[(j * 2 + 0) * 64 + lane];
            short8 kh1 = fKh[(j * 2 + 1) * 64 + lane];
            short8 kl0 = fKl[(j * 2 + 0) * 64 + lane];
            short8 kl1 = fKl[(j * 2 + 1) * 64 + lane];
            floatx4 a = (floatx4)0.0f;
            a = __builtin_amdgcn_mfma_f32_16x16x32_bf16(qfh[0], kh0, a, 0, 0, 0);
            a = __builtin_amdgcn_mfma_f32_16x16x32_bf16(qfh[1], kh1, a, 0, 0, 0);
            a = __builtin_amdgcn_mfma_f32_16x16x32_bf16(qfh[0], kl0, a, 0, 0, 0);
            a = __builtin_amdgcn_mfma_f32_16x16x32_bf16(qfh[1], kl1, a, 0, 0, 0);
            a = __builtin_amdgcn_mfma_f32_16x16x32_bf16(qfl[0], kh0, a, 0, 0, 0);
            a = __builtin_amdgcn_mfma_f32_16x16x32_bf16(qfl[1], kh1, a, 0, 0, 0);
            S[j] = a;
        }

        // scale + causal mask
#pragma unroll
        for (int j = 0; j < 4; j++)
#pragma unroll
            for (int r = 0; r < 4; r++) {
                float v = S[j][r] * 0.125f;
                if (needmask && (k0 + j * 16 + r15) > (qrow_base + hq * 4 + r)) v = -INFINITY;
                S[j][r] = v;
            }

        // online softmax (row-reduce across the 16-lane col group)
        float alpha[4];
#pragma unroll
        for (int r = 0; r < 4; r++) {
            float mt = fmaxf(fmaxf(S[0][r], S[1][r]), fmaxf(S[2][r], S[3][r]));
#pragma unroll
            for (int off = 1; off < 16; off <<= 1) mt = fmaxf(mt, __shfl_xor(mt, off));
            float mn = fmaxf(m_[r], mt);
            alpha[r] = __expf(m_[r] - mn);
            m_[r] = mn;
        }
        float rowsum[4] = {0.f, 0.f, 0.f, 0.f};
#pragma unroll
        for (int j = 0; j < 4; j++)
#pragma unroll
            for (int r = 0; r < 4; r++) {
                float p = __expf(S[j][r] - m_[r]);
                S[j][r] = p;
                rowsum[r] += p;
            }
#pragma unroll
        for (int r = 0; r < 4; r++) {
#pragma unroll
            for (int off = 1; off < 16; off <<= 1) rowsum[r] += __shfl_xor(rowsum[r], off);
            l_[r] = l_[r] * alpha[r] + rowsum[r];
        }
#pragma unroll
        for (int jd = 0; jd < 4; jd++)
#pragma unroll
            for (int r = 0; r < 4; r++) O[jd][r] *= alpha[r];

        // P (D-layout) -> LDS (A-layout, XOR-swizzled), split hi/lo
        char* pw0 = (char*)&P_s[w][0][0];
        char* pw1 = (char*)&P_s[w][1][0];
#pragma unroll
        for (int j = 0; j < 4; j++)
#pragma unroll
            for (int r = 0; r < 4; r++) {
                int prow = hq * 4 + r;
                unsigned byte = (unsigned)(prow * 128 + (j * 16 + r15) * 2) ^ ((prow & 7) << 4);
                unsigned short ph, pl;
                splitf(S[j][r], ph, pl);
                *(unsigned short*)(pw0 + byte) = ph;
                *(unsigned short*)(pw1 + byte) = pl;
            }
        short8 pah[2], pal[2];
#pragma unroll
        for (int c = 0; c < 2; c++) {
            unsigned byte = (unsigned)(r15 * 128 + c * 64 + hq * 16) ^ ((r15 & 7) << 4);
            pah[c] = *(const short8*)(pw0 + byte);
            pal[c] = *(const short8*)(pw1 + byte);
        }

        // O += P V
#pragma unroll
        for (int jd = 0; jd < 4; jd++) {
            short8 vh0 = fVh[(jd * 2 + 0) * 64 + lane];
            short8 vh1 = fVh[(jd * 2 + 1) * 64 + lane];
            short8 vl0 = fVl[(jd * 2 + 0) * 64 + lane];
            short8 vl1 = fVl[(jd * 2 + 1) * 64 + lane];
            floatx4 a = O[jd];
            a = __builtin_amdgcn_mfma_f32_16x16x32_bf16(pah[0], vh0, a, 0, 0, 0);
            a = __builtin_amdgcn_mfma_f32_16x16x32_bf16(pah[1], vh1, a, 0, 0, 0);
            a = __builtin_amdgcn_mfma_f32_16x16x32_bf16(pah[0], vl0, a, 0, 0, 0);
            a = __builtin_amdgcn_mfma_f32_16x16x32_bf16(pah[1], vl1, a, 0, 0, 0);
            a = __builtin_amdgcn_mfma_f32_16x16x32_bf16(pal[0], vh0, a, 0, 0, 0);
            a = __builtin_amdgcn_mfma_f32_16x16x32_bf16(pal[1], vh1, a, 0, 0, 0);
            O[jd] = a;
        }
    }

    // normalize + write y hi/lo
#pragma unroll
    for (int r = 0; r < 4; r++) l_[r] = 1.0f / l_[r];
#pragma unroll
    for (int jd = 0; jd < 4; jd++)
#pragma unroll
        for (int r = 0; r < 4; r++) {
            int t   = q0 + w * 16 + hq * 4 + r;
            int col = h * 64 + jd * 16 + r15;
            float v = O[jd][r] * l_[r];
            unsigned short hh, ll;
            splitf(v, hh, ll);
            size_t o = ((size_t)b * 2048 + t) * 1024 + col;
            yh[o] = hh;
            yl[o] = ll;
        }
}

// ---------------------------------------------------------------------------
extern "C" void kernel_launch(void* const* d_in, const int* in_sizes, int n_in,
                              void* d_out, int out_size, void* d_ws, size_t ws_size,
                              hipStream_t stream) {
    const float* x        = (const float*)d_in[0];
    const float* w_attn   = (const float*)d_in[1];
    const float* w_proj   = (const float*)d_in[2];
    const float* w_fc     = (const float*)d_in[3];
    const float* w_fcproj = (const float*)d_in[4];
    const float* ln1_w    = (const float*)d_in[5];
    const float* ln1_b    = (const float*)d_in[6];
    const float* ln2_w    = (const float*)d_in[7];
    const float* ln2_b    = (const float*)d_in[8];
    float* out = (float*)d_out;

    char* ws = (char*)d_ws;
    const size_t MB = 1048576;
    unsigned short* Qh   = (unsigned short*)(ws + 0 * MB);    // 8 MB each
    unsigned short* Ql   = (unsigned short*)(ws + 8 * MB);
    unsigned short* Kh   = (unsigned short*)(ws + 16 * MB);
    unsigned short* Kl   = (unsigned short*)(ws + 24 * MB);
    unsigned short* Vth  = (unsigned short*)(ws + 32 * MB);
    unsigned short* Vtl  = (unsigned short*)(ws + 40 * MB);
    unsigned short* acth = (unsigned short*)(ws + 0 * MB);    // 32 MB, reuses Q/K
    unsigned short* actl = (unsigned short*)(ws + 32 * MB);   // 32 MB, reuses Vt
    float*          x1   = (float*)(ws + 64 * MB);            // 16 MB
    unsigned short* ln_h = (unsigned short*)(ws + 80 * MB);   // 8 MB (dead after fc)
    unsigned short* ln_l = (unsigned short*)(ws + 88 * MB);
    unsigned short* yb_h = (unsigned short*)(ws + 96 * MB);   // 8 MB (dead after proj)
    unsigned short* yb_l = (unsigned short*)(ws + 104 * MB);
    float* part0 = (float*)(ws + 80 * MB);   // 16 MB, reuses ln region (fcproj stage)
    float* part1 = (float*)(ws + 96 * MB);   // 16 MB, reuses yb region
    unsigned short* wat_h  = (unsigned short*)(ws + 112 * MB);  // 6 MB
    unsigned short* wat_l  = (unsigned short*)(ws + 118 * MB);
    unsigned short* wpt_h  = (unsigned short*)(ws + 124 * MB);  // 2 MB
    unsigned short* wpt_l  = (unsigned short*)(ws + 126 * MB);
    unsigned short* wft_h  = (unsigned short*)(ws + 128 * MB);  // 8 MB
    unsigned short* wft_l  = (unsigned short*)(ws + 136 * MB);
    unsigned short* wfpt_h = (unsigned short*)(ws + 144 * MB);  // 8 MB
    unsigned short* wfpt_l = (unsigned short*)(ws + 152 * MB);  // ends 160 MB

    // weight convert+transpose
    wtrans_kernel<<<dim3(48, 16), 256, 0, stream>>>(w_attn,   wat_h,  wat_l,  1024, 3072);
    wtrans_kernel<<<dim3(16, 16), 256, 0, stream>>>(w_proj,   wpt_h,  wpt_l,  1024, 1024);
    wtrans_kernel<<<dim3(64, 16), 256, 0, stream>>>(w_fc,     wft_h,  wft_l,  1024, 4096);
    wtrans_kernel<<<dim3(16, 64), 256, 0, stream>>>(w_fcproj, wfpt_h, wfpt_l, 4096, 1024);

    // 1. ln1(x)
    ln_kernel<<<M_, 256, 0, stream>>>(x, ln1_w, ln1_b, ln_h, ln_l);
    // 2. qkv GEMM with scatter epilogue -> Q,K [B,H,T,64]; V^T [B,H,64,T]
    mfma_gemm<3><<<dim3(24, 32), 256, 0, stream>>>(
        ln_h, ln_l, wat_h, wat_l, nullptr, nullptr,
        Qh, Ql, Kh, Kl, Vth, Vtl, 3072, 1024, 1024);
    // 3. MFMA flash attention -> yb hi/lo
    attn_mfma<<<dim3(16, 32), 512, 0, stream>>>(Qh, Ql, Kh, Kl, Vth, Vtl, yb_h, yb_l);
    // 4. x1 = yb @ w_proj + x
    mfma_gemm<1><<<dim3(8, 32), 256, 0, stream>>>(
        yb_h, yb_l, wpt_h, wpt_l, x, x1,
        nullptr, nullptr, nullptr, nullptr, nullptr, nullptr, 1024, 1024, 1024);
    // 5. ln2(x1)
    ln_kernel<<<M_, 256, 0, stream>>>(x1, ln2_w, ln2_b, ln_h, ln_l);
    // 6. act = gelu(ln2 @ w_fc)
    mfma_gemm<2><<<dim3(32, 32), 256, 0, stream>>>(
        ln_h, ln_l, wft_h, wft_l, nullptr, nullptr,
        acth, actl, nullptr, nullptr, nullptr, nullptr, 4096, 1024, 1024);
    // 7. split-K=2: partials = act @ w_fcproj halves  (ln/yb regions are dead now)
    mfma_gemm<0><<<dim3(8, 32, 2), 256, 0, stream>>>(
        acth, actl, wfpt_h, wfpt_l, nullptr, part0,
        nullptr, nullptr, nullptr, nullptr, nullptr, nullptr, 1024, 2048, 4096);
    // 8. out = part0 + part1 + x1
    combine_kernel<<<4096, 256, 0, stream>>>(part0, part1, x1, out);
}

// Round 5
// 712.025 us; speedup vs baseline: 2.8407x; 1.0625x over previous
//
#include <hip/hip_runtime.h>
#include <math.h>

#define B_   2
#define T_   2048
#define C_   1024
#define H_   16
#define HD_  64
#define M_   (B_ * T_)   // 4096

typedef __attribute__((ext_vector_type(8))) short short8;
typedef __attribute__((ext_vector_type(4))) float floatx4;
typedef __attribute__((ext_vector_type(8))) unsigned short ushort8v;

// split fp32 -> bf16 hi (RNE) + bf16 lo (RNE of remainder)
__device__ __forceinline__ void splitf(float x, unsigned short& h, unsigned short& l) {
    unsigned u  = __float_as_uint(x);
    unsigned hr = (u + 0x7fffu + ((u >> 16) & 1u)) >> 16;
    h = (unsigned short)hr;
    float r = x - __uint_as_float(hr << 16);
    unsigned ur = __float_as_uint(r);
    l = (unsigned short)((ur + 0x7fffu + ((ur >> 16) & 1u)) >> 16);
}

__device__ __forceinline__ void gload16(const void* g, void* l) {
    __builtin_amdgcn_global_load_lds(
        (const __attribute__((address_space(1))) unsigned int*)g,
        (__attribute__((address_space(3))) unsigned int*)l, 16, 0, 0);
}

__device__ __forceinline__ float gelu_f(float x) {
    const float c = 0.7978845608028654f;  // sqrt(2/pi)
    float x3 = x * x * x;
    return 0.5f * x * (1.0f + tanhf(c * (x + 0.044715f * x3)));
}

// ---------------------------------------------------------------------------
// LayerNorm: one block per row, outputs hi/lo bf16.
// ---------------------------------------------------------------------------
__global__ __launch_bounds__(256) void ln_kernel(const float* __restrict__ x,
                                                 const float* __restrict__ w,
                                                 const float* __restrict__ b,
                                                 unsigned short* __restrict__ oh,
                                                 unsigned short* __restrict__ ol) {
    int row = blockIdx.x;
    int t   = threadIdx.x;
    const float4* xr = (const float4*)(x + (size_t)row * C_);
    float4 v = xr[t];
    float s  = v.x + v.y + v.z + v.w;
    float sq = v.x * v.x + v.y * v.y + v.z * v.z + v.w * v.w;
#pragma unroll
    for (int off = 32; off > 0; off >>= 1) {
        s  += __shfl_down(s,  off);
        sq += __shfl_down(sq, off);
    }
    __shared__ float ss[4], ssq[4];
    int wid = t >> 6, lane = t & 63;
    if (lane == 0) { ss[wid] = s; ssq[wid] = sq; }
    __syncthreads();
    float S  = ss[0] + ss[1] + ss[2] + ss[3];
    float SQ = ssq[0] + ssq[1] + ssq[2] + ssq[3];
    float mu   = S * (1.0f / C_);
    float var  = SQ * (1.0f / C_) - mu * mu;
    float rstd = rsqrtf(var + 1e-5f);
    float4 wv = ((const float4*)w)[t];
    float4 bv = ((const float4*)b)[t];
    float o0 = (v.x - mu) * rstd * wv.x + bv.x;
    float o1 = (v.y - mu) * rstd * wv.y + bv.y;
    float o2 = (v.z - mu) * rstd * wv.z + bv.z;
    float o3 = (v.w - mu) * rstd * wv.w + bv.w;
    ushort4 hv, lv;
    splitf(o0, hv.x, lv.x); splitf(o1, hv.y, lv.y);
    splitf(o2, hv.z, lv.z); splitf(o3, hv.w, lv.w);
    *(ushort4*)(oh + (size_t)row * C_ + t * 4) = hv;
    *(ushort4*)(ol + (size_t)row * C_ + t * 4) = lv;
}

// ---------------------------------------------------------------------------
// Weight convert + transpose: W [K][N] f32 -> Wt_hi/lo [N][K] bf16.
// ---------------------------------------------------------------------------
__global__ __launch_bounds__(256) void wtrans_kernel(const float* __restrict__ W,
                                                     unsigned short* __restrict__ th,
                                                     unsigned short* __restrict__ tl,
                                                     int K, int N) {
    __shared__ unsigned int tile[64][65];  // hi | lo<<16
    int n0 = blockIdx.x * 64, k0 = blockIdx.y * 64;
    int t  = threadIdx.x;
    int tc = (t & 15) * 4, tr = t >> 4;
#pragma unroll
    for (int it = 0; it < 4; it++) {
        int kr = it * 16 + tr;
        float4 v = *(const float4*)(W + (size_t)(k0 + kr) * N + n0 + tc);
        unsigned short hh, ll;
        splitf(v.x, hh, ll); tile[kr][tc + 0] = (unsigned)hh | ((unsigned)ll << 16);
        splitf(v.y, hh, ll); tile[kr][tc + 1] = (unsigned)hh | ((unsigned)ll << 16);
        splitf(v.z, hh, ll); tile[kr][tc + 2] = (unsigned)hh | ((unsigned)ll << 16);
        splitf(v.w, hh, ll); tile[kr][tc + 3] = (unsigned)hh | ((unsigned)ll << 16);
    }
    __syncthreads();
    int nl = t >> 2, kc = (t & 3) * 16;
    ushort8v h0, h1, l0, l1;
#pragma unroll
    for (int e = 0; e < 8; e++) {
        unsigned u = tile[kc + e][nl];
        h0[e] = (unsigned short)(u & 0xffff); l0[e] = (unsigned short)(u >> 16);
    }
#pragma unroll
    for (int e = 0; e < 8; e++) {
        unsigned u = tile[kc + 8 + e][nl];
        h1[e] = (unsigned short)(u & 0xffff); l1[e] = (unsigned short)(u >> 16);
    }
    size_t o = (size_t)(n0 + nl) * K + k0 + kc;
    *(ushort8v*)(th + o)     = h0;
    *(ushort8v*)(th + o + 8) = h1;
    *(ushort8v*)(tl + o)     = l0;
    *(ushort8v*)(tl + o + 8) = l1;
}

// ---------------------------------------------------------------------------
// 128x128 split-bf16 MFMA GEMM, 2-phase prefetch. Used for proj (EPI 1).
// ---------------------------------------------------------------------------
template <int EPI>
__global__ __launch_bounds__(256) void mfma_gemm(
    const unsigned short* __restrict__ Ah, const unsigned short* __restrict__ Al,
    const unsigned short* __restrict__ Bh, const unsigned short* __restrict__ Bl,
    const float* __restrict__ R, float* __restrict__ Cf,
    int N, int K, int Kstride) {
    __shared__ unsigned short lAh[2][4096], lAl[2][4096];
    __shared__ unsigned short lBh[2][4096], lBl[2][4096];
    int tid = threadIdx.x, lane = tid & 63, w = tid >> 6;
    int wr = w >> 1, wc = w & 1;

    int nx = gridDim.x;
    int nwg = nx * gridDim.y;
    int bid = blockIdx.y * nx + blockIdx.x;
    int q8  = nwg >> 3;
    int swz = (bid & 7) * q8 + (bid >> 3);
    int bm = (swz / nx) * 128, bn = (swz % nx) * 128;

    int r15 = lane & 15, hq = lane >> 4;

    floatx4 acc[4][4];
#pragma unroll
    for (int i = 0; i < 4; i++)
#pragma unroll
        for (int j = 0; j < 4; j++) acc[i][j] = (floatx4)0.0f;

    auto STAGE = [&](int buf, int k0) {
#pragma unroll
        for (int s = 0; s < 2; s++) {
            int sf = 2 * w + s;
            size_t arow = (size_t)(bm + sf * 16 + r15) * Kstride + k0 + hq * 8;
            size_t brow = (size_t)(bn + sf * 16 + r15) * Kstride + k0 + hq * 8;
            gload16(Ah + arow, &lAh[buf][sf * 512]);
            gload16(Al + arow, &lAl[buf][sf * 512]);
            gload16(Bh + brow, &lBh[buf][sf * 512]);
            gload16(Bl + brow, &lBl[buf][sf * 512]);
        }
    };

    STAGE(0, 0);
    __syncthreads();
    int cur = 0;
    int nt = K / 32;
    for (int t = 0; t < nt; t++) {
        if (t + 1 < nt) STAGE(cur ^ 1, (t + 1) * 32);
        const short8* fAh = (const short8*)&lAh[cur][0];
        const short8* fAl = (const short8*)&lAl[cur][0];
        const short8* fBh = (const short8*)&lBh[cur][0];
        const short8* fBl = (const short8*)&lBl[cur][0];
        short8 a_h[4], a_l[4], b_h[4], b_l[4];
#pragma unroll
        for (int i = 0; i < 4; i++) {
            a_h[i] = fAh[(wr * 4 + i) * 64 + lane];
            a_l[i] = fAl[(wr * 4 + i) * 64 + lane];
            b_h[i] = fBh[(wc * 4 + i) * 64 + lane];
            b_l[i] = fBl[(wc * 4 + i) * 64 + lane];
        }
        __builtin_amdgcn_s_setprio(1);
#pragma unroll
        for (int i = 0; i < 4; i++)
#pragma unroll
            for (int j = 0; j < 4; j++) {
                acc[i][j] = __builtin_amdgcn_mfma_f32_16x16x32_bf16(a_h[i], b_h[j], acc[i][j], 0, 0, 0);
                acc[i][j] = __builtin_amdgcn_mfma_f32_16x16x32_bf16(a_h[i], b_l[j], acc[i][j], 0, 0, 0);
                acc[i][j] = __builtin_amdgcn_mfma_f32_16x16x32_bf16(a_l[i], b_h[j], acc[i][j], 0, 0, 0);
            }
        __builtin_amdgcn_s_setprio(0);
        __syncthreads();
        cur ^= 1;
    }

    int er = hq * 4, ec = r15;
#pragma unroll
    for (int i = 0; i < 4; i++)
#pragma unroll
        for (int j = 0; j < 4; j++) {
            int row0 = bm + wr * 64 + i * 16 + er;
            int col  = bn + wc * 64 + j * 16 + ec;
#pragma unroll
            for (int r = 0; r < 4; r++) {
                int row = row0 + r;
                Cf[(size_t)row * N + col] = acc[i][j][r] + R[(size_t)row * N + col];
            }
        }
}

// ---------------------------------------------------------------------------
// 256x256 split-bf16 MFMA GEMM, 2-phase prefetch, 8 waves (2Mx4N), BK=32,
// 128 KB double-buffered LDS. EPI: 0 = split-K partial f32 store;
// 2 = gelu -> hi/lo bf16; 3 = qkv scatter.
// ---------------------------------------------------------------------------
template <int EPI>
__global__ __launch_bounds__(512, 2) void mfma_gemm256(
    const unsigned short* __restrict__ Ah, const unsigned short* __restrict__ Al,
    const unsigned short* __restrict__ Bh, const unsigned short* __restrict__ Bl,
    float* __restrict__ Cf,
    unsigned short* __restrict__ Ch, unsigned short* __restrict__ Cl,
    unsigned short* __restrict__ K2h, unsigned short* __restrict__ K2l,
    unsigned short* __restrict__ V2h, unsigned short* __restrict__ V2l,
    int N, int K, int Kstride) {
    __shared__ unsigned short lAh[2][8192], lAl[2][8192];   // 256 rows x 32 k
    __shared__ unsigned short lBh[2][8192], lBl[2][8192];   // 128 KB total
    int tid = threadIdx.x, lane = tid & 63, w = tid >> 6;   // w in 0..7
    int wr = w >> 2, wc = w & 3;                            // 2M x 4N waves

    int nx = gridDim.x;
    int nwg = nx * gridDim.y;
    int bid = blockIdx.y * nx + blockIdx.x;
    int q8  = nwg >> 3;
    int swz = (bid & 7) * q8 + (bid >> 3);
    int bm = (swz / nx) * 256, bn = (swz % nx) * 256;

    int kb = blockIdx.z * K;
    if (EPI == 0) Cf += (size_t)blockIdx.z * (size_t)gridDim.y * 256 * N;

    int r15 = lane & 15, hq = lane >> 4;

    floatx4 acc[8][4];
#pragma unroll
    for (int i = 0; i < 8; i++)
#pragma unroll
        for (int j = 0; j < 4; j++) acc[i][j] = (floatx4)0.0f;

    auto STAGE = [&](int buf, int k0) {
#pragma unroll
        for (int s = 0; s < 2; s++) {
            int sf = 2 * w + s;   // 16 subtiles of 16 rows each
            size_t arow = (size_t)(bm + sf * 16 + r15) * Kstride + kb + k0 + hq * 8;
            size_t brow = (size_t)(bn + sf * 16 + r15) * Kstride + kb + k0 + hq * 8;
            gload16(Ah + arow, &lAh[buf][sf * 512]);
            gload16(Al + arow, &lAl[buf][sf * 512]);
            gload16(Bh + brow, &lBh[buf][sf * 512]);
            gload16(Bl + brow, &lBl[buf][sf * 512]);
        }
    };

    STAGE(0, 0);
    __syncthreads();
    int cur = 0;
    int nt = K / 32;
    for (int t = 0; t < nt; t++) {
        if (t + 1 < nt) STAGE(cur ^ 1, (t + 1) * 32);
        const short8* fAh = (const short8*)&lAh[cur][0];
        const short8* fAl = (const short8*)&lAl[cur][0];
        const short8* fBh = (const short8*)&lBh[cur][0];
        const short8* fBl = (const short8*)&lBl[cur][0];
        short8 b_h[4], b_l[4];
#pragma unroll
        for (int j = 0; j < 4; j++) {
            b_h[j] = fBh[(wc * 4 + j) * 64 + lane];
            b_l[j] = fBl[(wc * 4 + j) * 64 + lane];
        }
        __builtin_amdgcn_s_setprio(1);
#pragma unroll
        for (int i = 0; i < 8; i++) {
            short8 a_h = fAh[(wr * 8 + i) * 64 + lane];
            short8 a_l = fAl[(wr * 8 + i) * 64 + lane];
#pragma unroll
            for (int j = 0; j < 4; j++) {
                acc[i][j] = __builtin_amdgcn_mfma_f32_16x16x32_bf16(a_h, b_h[j], acc[i][j], 0, 0, 0);
                acc[i][j] = __builtin_amdgcn_mfma_f32_16x16x32_bf16(a_h, b_l[j], acc[i][j], 0, 0, 0);
                acc[i][j] = __builtin_amdgcn_mfma_f32_16x16x32_bf16(a_l, b_h[j], acc[i][j], 0, 0, 0);
            }
        }
        __builtin_amdgcn_s_setprio(0);
        __syncthreads();
        cur ^= 1;
    }

    int er = hq * 4, ec = r15;
#pragma unroll
    for (int i = 0; i < 8; i++) {
#pragma unroll
        for (int j = 0; j < 4; j++) {
            int row0 = bm + wr * 128 + i * 16 + er;
            int col  = bn + wc * 64 + j * 16 + ec;
            if (EPI == 0) {
#pragma unroll
                for (int r = 0; r < 4; r++)
                    Cf[(size_t)(row0 + r) * N + col] = acc[i][j][r];
            } else if (EPI == 2) {
#pragma unroll
                for (int r = 0; r < 4; r++) {
                    int row = row0 + r;
                    float g = gelu_f(acc[i][j][r]);
                    unsigned short hh, ll;
                    splitf(g, hh, ll);
                    Ch[(size_t)row * N + col] = hh;
                    Cl[(size_t)row * N + col] = ll;
                }
            } else {  // EPI == 3: qkv scatter
                int region = bn >> 10;   // uniform per block (256 | 1024)
                int b_ = row0 >> 11;
                int h_ = (col >> 6) & 15;
                int d_ = col & 63;
                size_t bh_ = (size_t)(b_ * 16 + h_);
                if (region == 2) {
                    ushort4 hv, lv;
                    splitf(acc[i][j][0], hv.x, lv.x);
                    splitf(acc[i][j][1], hv.y, lv.y);
                    splitf(acc[i][j][2], hv.z, lv.z);
                    splitf(acc[i][j][3], hv.w, lv.w);
                    size_t o = (bh_ * 64 + d_) * 2048 + (row0 & 2047);
                    *(ushort4*)(V2h + o) = hv;
                    *(ushort4*)(V2l + o) = lv;
                } else {
                    unsigned short* dh = (region == 0) ? Ch : K2h;
                    unsigned short* dl = (region == 0) ? Cl : K2l;
#pragma unroll
                    for (int r = 0; r < 4; r++) {
                        int t_ = (row0 + r) & 2047;
                        unsigned short hh, ll;
                        splitf(acc[i][j][r], hh, ll);
                        size_t o = (bh_ * 2048 + t_) * 64 + d_;
                        dh[o] = hh;
                        dl[o] = ll;
                    }
                }
            }
        }
    }
}

// ---------------------------------------------------------------------------
// split-K=4 combine: out = p0+p1+p2+p3 + residual
// ---------------------------------------------------------------------------
__global__ __launch_bounds__(256) void combine4_kernel(const float* __restrict__ p0,
                                                       const float* __restrict__ p1,
                                                       const float* __restrict__ p2,
                                                       const float* __restrict__ p3,
                                                       const float* __restrict__ r,
                                                       float* __restrict__ out) {
    int i = blockIdx.x * 256 + threadIdx.x;
    float4 a = ((const float4*)p0)[i];
    float4 b = ((const float4*)p1)[i];
    float4 c = ((const float4*)p2)[i];
    float4 d = ((const float4*)p3)[i];
    float4 e = ((const float4*)r)[i];
    float4 o;
    o.x = a.x + b.x + c.x + d.x + e.x;
    o.y = a.y + b.y + c.y + d.y + e.y;
    o.z = a.z + b.z + c.z + d.z + e.z;
    o.w = a.w + b.w + c.w + d.w + e.w;
    ((float4*)out)[i] = o;
}

// ---------------------------------------------------------------------------
// Split-bf16 MFMA flash attention (causal). Q-tile 128 rows/block, 8 waves x
// 16 rows, KV-tile 64. Q,K [B,H,T,64] hi/lo, V [B,H,64,T] hi/lo (transposed).
// ---------------------------------------------------------------------------
__global__ __launch_bounds__(512) void attn_mfma(
    const unsigned short* __restrict__ Qh_g, const unsigned short* __restrict__ Ql_g,
    const unsigned short* __restrict__ Kh_g, const unsigned short* __restrict__ Kl_g,
    const unsigned short* __restrict__ Vh_g, const unsigned short* __restrict__ Vl_g,
    unsigned short* __restrict__ yh, unsigned short* __restrict__ yl) {
    __shared__ unsigned short Ks_h[4096], Ks_l[4096], Vs_h[4096], Vs_l[4096];  // 32 KB
    __shared__ unsigned short P_s[8][2][1024];  // per-wave 16x64 hi/lo, swizzled

    int qt  = 15 - (int)blockIdx.x;  // heavy tiles first
    int bh  = blockIdx.y;
    int b   = bh >> 4, h = bh & 15;
    int tid = threadIdx.x, lane = tid & 63, w = tid >> 6;
    int r15 = lane & 15, hq = lane >> 4;
    int q0  = qt * 128;
    int qrow_base = q0 + w * 16;
    size_t bhq = (size_t)bh * (2048 * 64);
    size_t bhv = (size_t)bh * (64 * 2048);

    short8 qfh[2], qfl[2];
    {
        size_t base = bhq + (size_t)(qrow_base + r15) * 64 + hq * 8;
        qfh[0] = *(const short8*)(Qh_g + base);
        qfh[1] = *(const short8*)(Qh_g + base + 32);
        qfl[0] = *(const short8*)(Ql_g + base);
        qfl[1] = *(const short8*)(Ql_g + base + 32);
    }

    floatx4 O[4];
    float m_[4], l_[4];
#pragma unroll
    for (int j = 0; j < 4; j++) O[j] = (floatx4)0.0f;
#pragma unroll
    for (int r = 0; r < 4; r++) { m_[r] = -INFINITY; l_[r] = 0.0f; }

    const short8* fKh = (const short8*)Ks_h;
    const short8* fKl = (const short8*)Ks_l;
    const short8* fVh = (const short8*)Vs_h;
    const short8* fVl = (const short8*)Vs_l;

    int ktmax = 2 * qt + 1;
    int srb = w >> 1, scb = w & 1;
    for (int kt = 0; kt <= ktmax; kt++) {
        int k0 = kt * 64;
        __syncthreads();
        {
            size_t koff = bhq + (size_t)(k0 + srb * 16 + r15) * 64 + scb * 32 + hq * 8;
            size_t voff = bhv + (size_t)(srb * 16 + r15) * 2048 + k0 + scb * 32 + hq * 8;
            gload16(Kh_g + koff, &Ks_h[w * 512]);
            gload16(Kl_g + koff, &Ks_l[w * 512]);
            gload16(Vh_g + voff, &Vs_h[w * 512]);
            gload16(Vl_g + voff, &Vs_l[w * 512]);
        }
        __syncthreads();

        bool active = (k0 <= qrow_base + 15);
        if (!active) continue;
        bool needmask = (k0 + 63 > qrow_base);

        floatx4 S[4];
#pragma unroll
        for (int j = 0; j < 4; j++) {
            short8 kh0 = fKh[(j * 2 + 0) * 64 + lane];
            short8 kh1 = fKh[(j * 2 + 1) * 64 + lane];
            short8 kl0 = fKl[(j * 2 + 0) * 64 + lane];
            short8 kl1 = fKl[(j * 2 + 1) * 64 + lane];
            floatx4 a = (floatx4)0.0f;
            a = __builtin_amdgcn_mfma_f32_16x16x32_bf16(qfh[0], kh0, a, 0, 0, 0);
            a = __builtin_amdgcn_mfma_f32_16x16x32_bf16(qfh[1], kh1, a, 0, 0, 0);
            a = __builtin_amdgcn_mfma_f32_16x16x32_bf16(qfh[0], kl0, a, 0, 0, 0);
            a = __builtin_amdgcn_mfma_f32_16x16x32_bf16(qfh[1], kl1, a, 0, 0, 0);
            a = __builtin_amdgcn_mfma_f32_16x16x32_bf16(qfl[0], kh0, a, 0, 0, 0);
            a = __builtin_amdgcn_mfma_f32_16x16x32_bf16(qfl[1], kh1, a, 0, 0, 0);
            S[j] = a;
        }

#pragma unroll
        for (int j = 0; j < 4; j++)
#pragma unroll
            for (int r = 0; r < 4; r++) {
                float v = S[j][r] * 0.125f;
                if (needmask && (k0 + j * 16 + r15) > (qrow_base + hq * 4 + r)) v = -INFINITY;
                S[j][r] = v;
            }

        float alpha[4];
#pragma unroll
        for (int r = 0; r < 4; r++) {
            float mt = fmaxf(fmaxf(S[0][r], S[1][r]), fmaxf(S[2][r], S[3][r]));
#pragma unroll
            for (int off = 1; off < 16; off <<= 1) mt = fmaxf(mt, __shfl_xor(mt, off));
            float mn = fmaxf(m_[r], mt);
            alpha[r] = __expf(m_[r] - mn);
            m_[r] = mn;
        }
        float rowsum[4] = {0.f, 0.f, 0.f, 0.f};
#pragma unroll
        for (int j = 0; j < 4; j++)
#pragma unroll
            for (int r = 0; r < 4; r++) {
                float p = __expf(S[j][r] - m_[r]);
                S[j][r] = p;
                rowsum[r] += p;
            }
#pragma unroll
        for (int r = 0; r < 4; r++) {
#pragma unroll
            for (int off = 1; off < 16; off <<= 1) rowsum[r] += __shfl_xor(rowsum[r], off);
            l_[r] = l_[r] * alpha[r] + rowsum[r];
        }
#pragma unroll
        for (int jd = 0; jd < 4; jd++)
#pragma unroll
            for (int r = 0; r < 4; r++) O[jd][r] *= alpha[r];

        char* pw0 = (char*)&P_s[w][0][0];
        char* pw1 = (char*)&P_s[w][1][0];
#pragma unroll
        for (int j = 0; j < 4; j++)
#pragma unroll
            for (int r = 0; r < 4; r++) {
                int prow = hq * 4 + r;
                unsigned byte = (unsigned)(prow * 128 + (j * 16 + r15) * 2) ^ ((prow & 7) << 4);
                unsigned short ph, pl;
                splitf(S[j][r], ph, pl);
                *(unsigned short*)(pw0 + byte) = ph;
                *(unsigned short*)(pw1 + byte) = pl;
            }
        short8 pah[2], pal[2];
#pragma unroll
        for (int c = 0; c < 2; c++) {
            unsigned byte = (unsigned)(r15 * 128 + c * 64 + hq * 16) ^ ((r15 & 7) << 4);
            pah[c] = *(const short8*)(pw0 + byte);
            pal[c] = *(const short8*)(pw1 + byte);
        }

#pragma unroll
        for (int jd = 0; jd < 4; jd++) {
            short8 vh0 = fVh[(jd * 2 + 0) * 64 + lane];
            short8 vh1 = fVh[(jd * 2 + 1) * 64 + lane];
            short8 vl0 = fVl[(jd * 2 + 0) * 64 + lane];
            short8 vl1 = fVl[(jd * 2 + 1) * 64 + lane];
            floatx4 a = O[jd];
            a = __builtin_amdgcn_mfma_f32_16x16x32_bf16(pah[0], vh0, a, 0, 0, 0);
            a = __builtin_amdgcn_mfma_f32_16x16x32_bf16(pah[1], vh1, a, 0, 0, 0);
            a = __builtin_amdgcn_mfma_f32_16x16x32_bf16(pah[0], vl0, a, 0, 0, 0);
            a = __builtin_amdgcn_mfma_f32_16x16x32_bf16(pah[1], vl1, a, 0, 0, 0);
            a = __builtin_amdgcn_mfma_f32_16x16x32_bf16(pal[0], vh0, a, 0, 0, 0);
            a = __builtin_amdgcn_mfma_f32_16x16x32_bf16(pal[1], vh1, a, 0, 0, 0);
            O[jd] = a;
        }
    }

#pragma unroll
    for (int r = 0; r < 4; r++) l_[r] = 1.0f / l_[r];
#pragma unroll
    for (int jd = 0; jd < 4; jd++)
#pragma unroll
        for (int r = 0; r < 4; r++) {
            int t   = q0 + w * 16 + hq * 4 + r;
            int col = h * 64 + jd * 16 + r15;
            float v = O[jd][r] * l_[r];
            unsigned short hh, ll;
            splitf(v, hh, ll);
            size_t o = ((size_t)b * 2048 + t) * 1024 + col;
            yh[o] = hh;
            yl[o] = ll;
        }
}

// ---------------------------------------------------------------------------
extern "C" void kernel_launch(void* const* d_in, const int* in_sizes, int n_in,
                              void* d_out, int out_size, void* d_ws, size_t ws_size,
                              hipStream_t stream) {
    const float* x        = (const float*)d_in[0];
    const float* w_attn   = (const float*)d_in[1];
    const float* w_proj   = (const float*)d_in[2];
    const float* w_fc     = (const float*)d_in[3];
    const float* w_fcproj = (const float*)d_in[4];
    const float* ln1_w    = (const float*)d_in[5];
    const float* ln1_b    = (const float*)d_in[6];
    const float* ln2_w    = (const float*)d_in[7];
    const float* ln2_b    = (const float*)d_in[8];
    float* out = (float*)d_out;

    char* ws = (char*)d_ws;
    const size_t MB = 1048576;
    // liveness-packed layout (exactly 160 MB):
    unsigned short* Qh   = (unsigned short*)(ws + 0 * MB);    // 8 MB each
    unsigned short* Ql   = (unsigned short*)(ws + 8 * MB);
    unsigned short* Kh   = (unsigned short*)(ws + 16 * MB);
    unsigned short* Kl   = (unsigned short*)(ws + 24 * MB);
    unsigned short* Vth  = (unsigned short*)(ws + 32 * MB);
    unsigned short* Vtl  = (unsigned short*)(ws + 40 * MB);
    unsigned short* acth = (unsigned short*)(ws + 0 * MB);    // 32 MB, reuses Q/K (dead)
    unsigned short* actl = (unsigned short*)(ws + 32 * MB);   // 32 MB, reuses Vt (dead)
    float*          x1   = (float*)(ws + 64 * MB);            // 16 MB
    unsigned short* ln_h = (unsigned short*)(ws + 80 * MB);   // 8 MB
    unsigned short* ln_l = (unsigned short*)(ws + 88 * MB);
    unsigned short* yb_h = (unsigned short*)(ws + 96 * MB);   // 8 MB
    unsigned short* yb_l = (unsigned short*)(ws + 104 * MB);
    unsigned short* wat_h  = (unsigned short*)(ws + 112 * MB);  // 6 MB
    unsigned short* wat_l  = (unsigned short*)(ws + 118 * MB);
    unsigned short* wpt_h  = (unsigned short*)(ws + 124 * MB);  // 2 MB
    unsigned short* wpt_l  = (unsigned short*)(ws + 126 * MB);
    unsigned short* wft_h  = (unsigned short*)(ws + 128 * MB);  // 8 MB
    unsigned short* wft_l  = (unsigned short*)(ws + 136 * MB);
    unsigned short* wfpt_h = (unsigned short*)(ws + 144 * MB);  // 8 MB
    unsigned short* wfpt_l = (unsigned short*)(ws + 152 * MB);  // ends 160 MB
    // split-K partials (written at dispatch 7, after ln/yb/wat/wpt/wft are dead)
    float* part0 = (float*)(ws +  80 * MB);   // 16 MB each
    float* part1 = (float*)(ws +  96 * MB);
    float* part2 = (float*)(ws + 112 * MB);
    float* part3 = (float*)(ws + 128 * MB);

    // weight convert+transpose
    wtrans_kernel<<<dim3(48, 16), 256, 0, stream>>>(w_attn,   wat_h,  wat_l,  1024, 3072);
    wtrans_kernel<<<dim3(16, 16), 256, 0, stream>>>(w_proj,   wpt_h,  wpt_l,  1024, 1024);
    wtrans_kernel<<<dim3(64, 16), 256, 0, stream>>>(w_fc,     wft_h,  wft_l,  1024, 4096);
    wtrans_kernel<<<dim3(16, 64), 256, 0, stream>>>(w_fcproj, wfpt_h, wfpt_l, 4096, 1024);

    // 1. ln1(x)
    ln_kernel<<<M_, 256, 0, stream>>>(x, ln1_w, ln1_b, ln_h, ln_l);
    // 2. qkv GEMM (256^2) with scatter epilogue -> Q,K [B,H,T,64]; V^T [B,H,64,T]
    mfma_gemm256<3><<<dim3(12, 16), 512, 0, stream>>>(
        ln_h, ln_l, wat_h, wat_l, nullptr,
        Qh, Ql, Kh, Kl, Vth, Vtl, 3072, 1024, 1024);
    // 3. MFMA flash attention -> yb hi/lo
    attn_mfma<<<dim3(16, 32), 512, 0, stream>>>(Qh, Ql, Kh, Kl, Vth, Vtl, yb_h, yb_l);
    // 4. x1 = yb @ w_proj + x   (128^2 kernel)
    mfma_gemm<1><<<dim3(8, 32), 256, 0, stream>>>(
        yb_h, yb_l, wpt_h, wpt_l, x, x1, 1024, 1024, 1024);
    // 5. ln2(x1)
    ln_kernel<<<M_, 256, 0, stream>>>(x1, ln2_w, ln2_b, ln_h, ln_l);
    // 6. act = gelu(ln2 @ w_fc)  (256^2)
    mfma_gemm256<2><<<dim3(16, 16), 512, 0, stream>>>(
        ln_h, ln_l, wft_h, wft_l, nullptr,
        acth, actl, nullptr, nullptr, nullptr, nullptr, 4096, 1024, 1024);
    // 7. split-K=4 partials = act @ w_fcproj slices  (256^2)
    mfma_gemm256<0><<<dim3(4, 16, 4), 512, 0, stream>>>(
        acth, actl, wfpt_h, wfpt_l, part0,
        nullptr, nullptr, nullptr, nullptr, nullptr, nullptr, 1024, 1024, 4096);
    // 8. out = part0..3 + x1
    combine4_kernel<<<4096, 256, 0, stream>>>(part0, part1, part2, part3, x1, out);
}